// Round 12
// baseline (232.628 us; speedup 1.0000x reference)
//
#include <hip/hip_runtime.h>
#include <hip/hip_bf16.h>

typedef unsigned short u16;
typedef __attribute__((ext_vector_type(8))) short bf16x8;
typedef __attribute__((ext_vector_type(4))) short bf16x4;
typedef __attribute__((ext_vector_type(4))) float f32x4;

#define MFMA_BF16(a,b,c) __builtin_amdgcn_mfma_f32_16x16x32_bf16((a),(b),(c),0,0,0)
#define LOG2E 1.4426950408889634f

// K=16 bf16 MFMA: B-frag layout B[k=q*4+r][col=l15] == our P C-layout, so PV
// needs NO cross-lane exchange. Guarded: fall back to K32+bpermute if absent.
#if __has_builtin(__builtin_amdgcn_mfma_f32_16x16x16bf16_1k)
#define MFMA16(a,b,c) __builtin_amdgcn_mfma_f32_16x16x16bf16_1k((a),(b),(c),0,0,0)
#define HAVE_MFMA16 1
#elif __has_builtin(__builtin_amdgcn_mfma_f32_16x16x16_bf16)
#define MFMA16(a,b,c) __builtin_amdgcn_mfma_f32_16x16x16_bf16((a),(b),(c),0,0,0)
#define HAVE_MFMA16 1
#else
#define HAVE_MFMA16 0
#endif

__device__ __forceinline__ u16 f2b(float f) {
    __hip_bfloat16 h = __float2bfloat16(f);
    u16 u; __builtin_memcpy(&u, &h, 2); return u;
}
__device__ __forceinline__ f32x4 zero4() { f32x4 z = {0.f,0.f,0.f,0.f}; return z; }

// async global->LDS, 16B per lane. LDS dest = wave-uniform base + lane*16.
__device__ __forceinline__ void gl_lds16(const u16* g, u16* l) {
    __builtin_amdgcn_global_load_lds(
        (const __attribute__((address_space(1))) unsigned int*)g,
        (__attribute__((address_space(3))) unsigned int*)l,
        16, 0, 0);
}

// ------ fused preprocessing: packDist(+mask detect) | convX | convTW x2 ------
__global__ __launch_bounds__(256)
void prep(const float* __restrict__ x, u16* __restrict__ xb,
          const float* __restrict__ qkv_w, u16* __restrict__ wqkvT,
          const float* __restrict__ out_w, u16* __restrict__ woutT,
          const int* __restrict__ dist, const unsigned* __restrict__ mask,
          unsigned char* __restrict__ dist8) {
    __shared__ __align__(16) u16 T[64][68];
    __shared__ int sB, sH, sF;
    const int bid = blockIdx.x;
    const int tid = threadIdx.x;
    if (bid < 8192) {
        // ---- packDist: dist int32 -> u8 clipped [0,31]; masked (b,j) -> 32 ----
        if (tid == 0) { sB = 0; sH = 0; sF = 0; }
        __syncthreads();
        int lb = 0, lh = 0, lf = 0;
#pragma unroll
        for (int i = 0; i < 4; ++i) {
            unsigned v = mask[tid + i * 256];          // first 4KB: safe under all encodings
            if (v == 0x3f800000u) { lf = 1; }
            else if (v > 1u) {
                unsigned b0 = v & 0xffu, b1 = (v >> 8) & 0xffu, b2 = (v >> 16) & 0xffu, b3 = v >> 24;
                bool bytesOK = (b0 <= 1u) && (b1 <= 1u) && (b2 <= 1u) && (b3 <= 1u);
                unsigned h0 = v & 0xffffu, h1 = v >> 16;
                bool halfOK = (h0 == 0u || h0 == 0x3f80u) && (h1 == 0u || h1 == 0x3f80u);
                if (bytesOK) lb = 1; else if (halfOK) lh = 1;
            }
        }
        if (lb) atomicOr(&sB, 1);
        if (lh) atomicOr(&sH, 1);
        if (lf) atomicOr(&sF, 1);
        __syncthreads();
        int mode = sH ? 3 : (sB ? 1 : (sF ? 2 : 0));
        size_t i = ((size_t)bid * 256 + tid) * 4;
        int4 v = *(const int4*)(dist + i);
        int b = (int)(i >> 22), j = (int)(i & 2047);   // j multiple of 4, no row crossing
        int base = b * 2048 + j;
        int mk0, mk1, mk2, mk3;
        if (mode == 0) {
            int4 mv = *(const int4*)((const int*)mask + base);
            mk0 = mv.x != 0; mk1 = mv.y != 0; mk2 = mv.z != 0; mk3 = mv.w != 0;
        } else if (mode == 1) {
            const unsigned char* m8 = (const unsigned char*)mask;
            mk0 = m8[base] != 0; mk1 = m8[base+1] != 0; mk2 = m8[base+2] != 0; mk3 = m8[base+3] != 0;
        } else if (mode == 2) {
            float4 mv = *(const float4*)((const float*)mask + base);
            mk0 = mv.x != 0.f; mk1 = mv.y != 0.f; mk2 = mv.z != 0.f; mk3 = mv.w != 0.f;
        } else {
            const u16* mh = (const u16*)mask;
            mk0 = mh[base] != 0; mk1 = mh[base+1] != 0; mk2 = mh[base+2] != 0; mk3 = mh[base+3] != 0;
        }
        uchar4 o;
        o.x = mk0 ? 32 : (unsigned char)min(max(v.x, 0), 31);
        o.y = mk1 ? 32 : (unsigned char)min(max(v.y, 0), 31);
        o.z = mk2 ? 32 : (unsigned char)min(max(v.z, 0), 31);
        o.w = mk3 ? 32 : (unsigned char)min(max(v.w, 0), 31);
        *(uchar4*)(dist8 + i) = o;
    } else if (bid < 8192 + 1536) {
        // ---- convX: x f32 -> bf16, 8 elems/thread ----
        size_t i = ((size_t)(bid - 8192) * 256 + tid) * 8;
        float4 a = *(const float4*)(x + i);
        float4 b = *(const float4*)(x + i + 4);
        union { u16 s[8]; uint4 v; } u;
        u.s[0]=f2b(a.x); u.s[1]=f2b(a.y); u.s[2]=f2b(a.z); u.s[3]=f2b(a.w);
        u.s[4]=f2b(b.x); u.s[5]=f2b(b.y); u.s[6]=f2b(b.z); u.s[7]=f2b(b.w);
        *(uint4*)(xb + i) = u.v;
    } else {
        // ---- convTW: weight [768][C] f32 -> [C][768] bf16 transpose+convert ----
        const float* in; u16* out; int C, c0, k0;
        if (bid < 8192 + 1536 + 432) {
            int s = bid - (8192 + 1536);
            in = qkv_w; out = wqkvT; C = 2304;
            c0 = (s % 36) * 64; k0 = (s / 36) * 64;
        } else {
            int s = bid - (8192 + 1536 + 432);
            in = out_w; out = woutT; C = 768;
            c0 = (s % 12) * 64; k0 = (s / 12) * 64;
        }
#pragma unroll
        for (int i = 0; i < 4; ++i) {
            int id = tid + i * 256;
            int row = id >> 4, ch = id & 15;
            float4 v = *(const float4*)(in + (size_t)(k0 + row) * C + c0 + ch * 4);
            T[row][ch*4+0] = f2b(v.x); T[row][ch*4+1] = f2b(v.y);
            T[row][ch*4+2] = f2b(v.z); T[row][ch*4+3] = f2b(v.w);
        }
        __syncthreads();
#pragma unroll
        for (int i = 0; i < 2; ++i) {
            int id = tid + i * 256;
            int c = id >> 3, ch = id & 7;
            union { u16 s[8]; uint4 v; } u;
#pragma unroll
            for (int jj = 0; jj < 8; ++jj) u.s[jj] = T[ch*8+jj][c];
            *(uint4*)(out + (size_t)(c0 + c) * 768 + k0 + ch * 8) = u.v;
        }
    }
}

// ------ QKV GEMM: 64x128 tile, gl_lds double-buffer, vectorized epilogues ------
// Grid (18,64) = 1152 blocks = 4.5/CU (old 128x128 = 576 = 2.25/CU tail).
// which = n0/768 is BLOCK-UNIFORM (768%128==0): V blocks keep direct 8B
// transposed stores; Q/K blocks bounce acc -> LDS[64][128] bf16 and emit
// 4 coalesced uint4 stores/thread (old path: 64 scalar 2B stores per lane).
__global__ __launch_bounds__(256)
void gemmQKV(const u16* __restrict__ A, const u16* __restrict__ Bt,
             const float* __restrict__ bias,
             u16* __restrict__ qO, u16* __restrict__ kO, u16* __restrict__ vO) {
    __shared__ __align__(16) u16 As[2][64*32];
    __shared__ __align__(16) u16 Bs[2][128*32];
    __shared__ __align__(16) u16 Ls[64*128];
    const int K = 768;
    const int tid = threadIdx.x;
    const int lane = tid & 63, w = tid >> 6;
    const int l15 = lane & 15, q = lane >> 4;
    const int m0 = blockIdx.y * 64, n0 = blockIdx.x * 128;
    // staging (R10-proven swizzle pair): row%16 = lane>>2, src chunk XOR (lane>>3)&3
    const int stRow = lane >> 2;
    const int stChunk = (lane & 3) ^ ((lane >> 3) & 3);
    const u16* Ag = A + (size_t)(m0 + w*16 + stRow) * K + stChunk * 8;
    const u16* Bg = Bt + (size_t)(n0 + w*32 + stRow) * K + stChunk * 8;
    const int fA = (q ^ ((l15 >> 1) & 3)) * 8;      // read-side chunk swizzle

    f32x4 acc[4][2];
#pragma unroll
    for (int i=0;i<4;++i)
#pragma unroll
        for (int j=0;j<2;++j) acc[i][j] = zero4();

    // prologue: stage kt=0 into buf 0
    gl_lds16(Ag, &As[0][0] + w*16*32);
#pragma unroll
    for (int c = 0; c < 2; ++c)
        gl_lds16(Bg + (size_t)(c*16) * K, &Bs[0][0] + (w*32 + c*16)*32);
    __syncthreads();

    int cur = 0;
    for (int kt = 0; kt < 24; ++kt) {
        if (kt < 23) {
            const int ko = (kt + 1) * 32;
            gl_lds16(Ag + ko, &As[cur^1][0] + w*16*32);
#pragma unroll
            for (int c = 0; c < 2; ++c)
                gl_lds16(Bg + (size_t)(c*16) * K + ko, &Bs[cur^1][0] + (w*32 + c*16)*32);
        }
        const u16* as = &As[cur][0];
        const u16* bs = &Bs[cur][0];
        bf16x8 af[4], bfr[2];
#pragma unroll
        for (int mt=0; mt<4; ++mt) af[mt]  = *(const bf16x8*)(as + (mt*16+l15)*32 + fA);
#pragma unroll
        for (int nt=0; nt<2; ++nt) bfr[nt] = *(const bf16x8*)(bs + (w*32+nt*16+l15)*32 + fA);
#pragma unroll
        for (int mt=0; mt<4; ++mt)
#pragma unroll
            for (int nt=0; nt<2; ++nt)
                acc[mt][nt] = MFMA_BF16(af[mt], bfr[nt], acc[mt][nt]);
        __syncthreads();
        cur ^= 1;
    }

    const int which = n0 / 768;                      // block-uniform
    const int b = m0 >> 11, tokB = m0 & 2047;
    if (which == 2) {
        // V: direct transposed 8B stores (proven)
#pragma unroll
        for (int mt=0; mt<4; ++mt) {
#pragma unroll
            for (int nt=0; nt<2; ++nt) {
                int n = n0 + w*32 + nt*16 + l15;
                int rem = n - 1536;
                int hh = rem >> 6, hd = rem & 63;
                float bv = bias[n];
                int tok0 = tokB + mt*16 + q*4;
                union { u16 s4[4]; unsigned long long u; } pv;
#pragma unroll
                for (int r=0; r<4; ++r) pv.s4[r] = f2b(acc[mt][nt][r] + bv);
                *(unsigned long long*)(vO + ((size_t)(b*12 + hh)*64 + hd)*2048 + tok0) = pv.u;
            }
        }
    } else {
        // Q/K: bounce to LDS, then coalesced uint4 stores
        const float sc = (which == 0) ? (0.125f * LOG2E) : 1.0f;
#pragma unroll
        for (int mt=0; mt<4; ++mt) {
#pragma unroll
            for (int nt=0; nt<2; ++nt) {
                int nl = w*32 + nt*16 + l15;
                float bv = bias[n0 + nl];
#pragma unroll
                for (int r=0; r<4; ++r)
                    Ls[(mt*16 + q*4 + r)*128 + nl] = f2b((acc[mt][nt][r] + bv) * sc);
            }
        }
        __syncthreads();
        u16* dst = (which == 0) ? qO : kO;
        const int h0 = (n0 - which*768) >> 6;        // 2 heads per block
#pragma unroll
        for (int k = 0; k < 4; ++k) {
            int idx = k*256 + tid;
            int row = idx >> 4, rem = idx & 15;
            int hh = rem >> 3, c = rem & 7;
            uint4 v = *(const uint4*)(Ls + row*128 + hh*64 + c*8);
            *(uint4*)(dst + ((size_t)(b*12 + h0 + hh)*2048 + tokB + row)*64 + c*8) = v;
        }
    }
}

// ------ output GEMM: 64x64 tiles, grid (12,64)=768 blocks = 3 blocks/CU ------
__global__ __launch_bounds__(256)
void gemmOut(const u16* __restrict__ A, const u16* __restrict__ Bt,
             const float* __restrict__ bias, float* __restrict__ fO) {
    __shared__ __align__(16) u16 As[2][64*32];
    __shared__ __align__(16) u16 Bs[2][64*32];
    const int K = 768;
    const int tid = threadIdx.x;
    const int lane = tid & 63, w = tid >> 6;
    const int l15 = lane & 15, q = lane >> 4;
    const int m0 = blockIdx.y * 64, n0 = blockIdx.x * 64;
    const int stRow = tid >> 2;                        // 0..63
    const int stChunk = (tid & 3) ^ ((tid >> 3) & 3);  // XOR by (row>>1)&3
    const u16* Ag = A + (size_t)(m0 + stRow) * K + stChunk * 8;
    const u16* Bg = Bt + (size_t)(n0 + stRow) * K + stChunk * 8;
    const int fA = (q ^ ((l15 >> 1) & 3)) * 8;

    f32x4 acc[4];
#pragma unroll
    for (int i=0;i<4;++i) acc[i] = zero4();

    gl_lds16(Ag, &As[0][0] + w*512);
    gl_lds16(Bg, &Bs[0][0] + w*512);
    __syncthreads();

    int cur = 0;
    for (int kt = 0; kt < 24; ++kt) {
        if (kt < 23) {
            const int ko = (kt + 1) * 32;
            gl_lds16(Ag + ko, &As[cur^1][0] + w*512);
            gl_lds16(Bg + ko, &Bs[cur^1][0] + w*512);
        }
        const u16* as = &As[cur][0];
        const u16* bs = &Bs[cur][0];
        bf16x8 af = *(const bf16x8*)(as + (w*16 + l15)*32 + fA);
        bf16x8 bfr[4];
#pragma unroll
        for (int nt=0; nt<4; ++nt) bfr[nt] = *(const bf16x8*)(bs + (nt*16+l15)*32 + fA);
#pragma unroll
        for (int nt=0; nt<4; ++nt) acc[nt] = MFMA_BF16(af, bfr[nt], acc[nt]);
        __syncthreads();
        cur ^= 1;
    }

#pragma unroll
    for (int nt=0; nt<4; ++nt) {
        int n = n0 + nt*16 + l15;
        float bv = bias[n];
#pragma unroll
        for (int r=0; r<4; ++r) {
            int m = m0 + w*16 + q*4 + r;
            fO[(size_t)m*768 + n] = acc[nt][r] + bv;
        }
    }
}

// ------ fused flash attention: LDS-staged K/V/dist, single-pass, K16-MFMA PV ------
// R12: threshold defer-max (T13, THR=8 in log2 domain) -- skip the o-rescale
// whenever all lanes' tile-max is within 8 of the running max; P bounded by
// 2^8, bf16 relative precision unchanged (HK-verified technique).
__global__ __launch_bounds__(256)
void flashAttn(const u16* __restrict__ Qb, const u16* __restrict__ Kb,
               const u16* __restrict__ Vt, const unsigned char* __restrict__ dist8,
               const float* __restrict__ btg, u16* __restrict__ attnout) {
    __shared__ float bt[33];
    __shared__ __align__(16) u16 KT[2][4096];   // [buf][64 j][64 d] swizzled
    __shared__ __align__(16) u16 VT[2][4096];   // [buf][64 d][64 j] swizzled
    __shared__ __align__(16) u16 DT[2][2048];   // [buf][64 i][64 j] u8, swizzled
    __shared__ __align__(16) u16 Os[4][16][72];
    const int tid = threadIdx.x;
    const int lane = tid & 63, w = tid >> 6;
    const int l15 = lane & 15, q = lane >> 4;
    // --- XCD-locality remap (bijective on [0,768)) ---
    const int wg = blockIdx.x + 32 * (blockIdx.y + 12 * blockIdx.z);
    const int xcd = wg & 7, slot = wg >> 3;
    const int g = ((slot >> 5) << 3) + xcd;            // group = (b,h), [0,24)
    const int i0 = (slot & 31) * 64;                   // i-block within group
    const int b = g / 12, h = g - b * 12;
    const int bh = g;
    const float NEG_INF = -__builtin_inff();
    if (tid < 33) bt[tid] = (tid == 32) ? NEG_INF : btg[tid*12 + h] * LOG2E;

    const int iRow = i0 + w*16 + l15;
    const u16* Qp = Qb + ((size_t)bh*2048 + iRow)*64;
    bf16x8 qB0 = *(const bf16x8*)(Qp + q*8);
    bf16x8 qB1 = *(const bf16x8*)(Qp + 32 + q*8);
#if !HAVE_MFMA16
    const int srcL0 = ((2*q)   & 3)*16 + l15;
    const int srcL1 = ((2*q+1) & 3)*16 + l15;
    union { unsigned u4[4]; bf16x8 v; } one_;
    { unsigned oc = (l15 == 0) ? 0x3F803F80u : 0u;
      one_.u4[0]=oc; one_.u4[1]=oc; one_.u4[2]=oc; one_.u4[3]=oc; }
#else
    union { unsigned u2[2]; bf16x4 v; } one4_;
    { unsigned oc = (l15 == 0) ? 0x3F803F80u : 0u;
      one4_.u2[0]=oc; one4_.u2[1]=oc; }
#endif

    // --- staging geometry: LDS linear dest, XOR-swizzled source ---
    const int stRow = w*16 + (lane >> 3);                       // K/V: + c*8
    const int stCol = (((lane & 7) ^ (lane >> 3)) << 4);        // K/V 16B chunk
    const int dRow = w*16 + (lane >> 2);                        // dist: 64 rows
    const int dCol = ((lane & 3) ^ ((lane >> 3) & 3)) << 4;     // dist 16B chunk
    const char* kgB = (const char*)Kb + (size_t)bh*2048*128;    // [tok][64d*2B]
    const char* vgB = (const char*)Vt + (size_t)bh*64*4096;     // [d][2048tok*2B]
    const unsigned char* dgB = dist8 + (size_t)(b*2048 + i0)*2048;
    const int swz = (l15 & 7) << 4;
    const int f0 = (q*16)      ^ swz;
    const int f1 = (q*16 + 64) ^ swz;
    const int rB = l15 * 128;
    const int rD = (w*16 + l15) * 64;                           // dist row base
    const int dsw = (l15 >> 1) & 3;                             // dist read swizzle

    // prologue: stage tile 0 into buf 0
    {
        u16* kd = &KT[0][0] + w*1024;
        u16* vd = &VT[0][0] + w*1024;
#pragma unroll
        for (int c = 0; c < 2; ++c) {
            int row = stRow + c*8;
            gl_lds16((const u16*)(kgB + (size_t)row*128 + stCol),  kd + c*512);
            gl_lds16((const u16*)(vgB + (size_t)row*4096 + stCol), vd + c*512);
        }
        gl_lds16((const u16*)(dgB + (size_t)dRow*2048 + dCol),
                 (u16*)((char*)&DT[0][0] + w*1024));
    }
    __syncthreads();

    f32x4 o0 = zero4(), o1 = zero4(), o2 = zero4(), o3 = zero4(), o4 = zero4();
    float mI = NEG_INF;
    int cur = 0;

    for (int jt = 0; jt < 32; ++jt) {
        const int j0 = jt * 64;
        // --- issue next tile's DMA first (hides under compute) ---
        if (jt < 31) {
            const int j0n = j0 + 64;
            u16* kd = &KT[cur^1][0] + w*1024;
            u16* vd = &VT[cur^1][0] + w*1024;
#pragma unroll
            for (int c = 0; c < 2; ++c) {
                int row = stRow + c*8;
                gl_lds16((const u16*)(kgB + (size_t)(j0n + row)*128 + stCol),          kd + c*512);
                gl_lds16((const u16*)(vgB + (size_t)row*4096 + (size_t)j0n*2 + stCol), vd + c*512);
            }
            gl_lds16((const u16*)(dgB + (size_t)dRow*2048 + j0n + dCol),
                     (u16*)((char*)&DT[cur^1][0] + w*1024));
        }
        // dist values from LDS (swizzled)
        const char* dt = (const char*)&DT[cur][0];
        unsigned dv4[4];
#pragma unroll
        for (int mt = 0; mt < 4; ++mt)
            dv4[mt] = *(const unsigned*)(dt + rD + ((mt ^ dsw) << 4) + q*4);

        // --- S^T = K·Q^T from LDS ---
        const char* kt = (const char*)&KT[cur][0];
        f32x4 s0 = zero4(), s1 = zero4(), s2 = zero4(), s3 = zero4();
        {
            bf16x8 k00 = *(const bf16x8*)(kt + rB          + f0);
            bf16x8 k01 = *(const bf16x8*)(kt + rB          + f1);
            bf16x8 k10 = *(const bf16x8*)(kt + rB + 2048   + f0);
            bf16x8 k11 = *(const bf16x8*)(kt + rB + 2048   + f1);
            bf16x8 k20 = *(const bf16x8*)(kt + rB + 4096   + f0);
            bf16x8 k21 = *(const bf16x8*)(kt + rB + 4096   + f1);
            bf16x8 k30 = *(const bf16x8*)(kt + rB + 6144   + f0);
            bf16x8 k31 = *(const bf16x8*)(kt + rB + 6144   + f1);
            __builtin_amdgcn_s_setprio(1);
            s0 = MFMA_BF16(k00, qB0, s0); s0 = MFMA_BF16(k01, qB1, s0);
            s1 = MFMA_BF16(k10, qB0, s1); s1 = MFMA_BF16(k11, qB1, s1);
            s2 = MFMA_BF16(k20, qB0, s2); s2 = MFMA_BF16(k21, qB1, s2);
            s3 = MFMA_BF16(k30, qB0, s3); s3 = MFMA_BF16(k31, qB1, s3);
            __builtin_amdgcn_s_setprio(0);
        }

        // --- bias gather applies mask too (dd==32 -> -inf) ---
        float sv[4][4];
#pragma unroll
        for (int mt = 0; mt < 4; ++mt) {
            const f32x4 sm = mt==0 ? s0 : (mt==1 ? s1 : (mt==2 ? s2 : s3));
            const unsigned d4 = dv4[mt];
#pragma unroll
            for (int r = 0; r < 4; ++r) {
                int dd = (d4 >> (r*8)) & 255;
                sv[mt][r] = sm[r] + bt[dd];
            }
        }

        // --- online max (tree + 2 cross-quad shfl) + THRESHOLD defer-rescale ---
        float t0 = fmaxf(fmaxf(sv[0][0], sv[0][1]), fmaxf(sv[0][2], sv[0][3]));
        float t1 = fmaxf(fmaxf(sv[1][0], sv[1][1]), fmaxf(sv[1][2], sv[1][3]));
        float t2 = fmaxf(fmaxf(sv[2][0], sv[2][1]), fmaxf(sv[2][2], sv[2][3]));
        float t3 = fmaxf(fmaxf(sv[3][0], sv[3][1]), fmaxf(sv[3][2], sv[3][3]));
        float rm = fmaxf(fmaxf(t0, t1), fmaxf(t2, t3));
        rm = fmaxf(rm, __shfl_xor(rm, 16, 64));
        rm = fmaxf(rm, __shfl_xor(rm, 32, 64));
        if (!__all(rm <= mI + 8.0f)) {               // T13: P bounded by 2^8
            float mn = fmaxf(mI, rm);
            float al = exp2f(mI - mn);
            mI = mn;
#pragma unroll
            for (int r = 0; r < 4; ++r) { o0[r] *= al; o1[r] *= al; o2[r] *= al; o3[r] *= al; }
            o4[0] *= al;
        }
        float p[4][4];
#pragma unroll
        for (int mt = 0; mt < 4; ++mt)
#pragma unroll
            for (int r = 0; r < 4; ++r) p[mt][r] = exp2f(sv[mt][r] - mI);

        const char* vt = (const char*)&VT[cur][0];
#if HAVE_MFMA16
        // --- pack P (C-layout == K16 B-frag layout) and PV, no exchange ---
        __builtin_amdgcn_s_setprio(1);
#pragma unroll
        for (int mt = 0; mt < 4; ++mt) {
            union { unsigned d[2]; bf16x4 v; } pu;
            pu.d[0] = (unsigned)f2b(p[mt][0]) | ((unsigned)f2b(p[mt][1]) << 16);
            pu.d[1] = (unsigned)f2b(p[mt][2]) | ((unsigned)f2b(p[mt][3]) << 16);
            const int cbase = (((mt*2 + (q>>1)) ^ (l15 & 7)) << 4) + (q & 1)*8;
            bf16x4 v0 = *(const bf16x4*)(vt + rB          + cbase);
            bf16x4 v1 = *(const bf16x4*)(vt + rB + 2048   + cbase);
            bf16x4 v2 = *(const bf16x4*)(vt + rB + 4096   + cbase);
            bf16x4 v3 = *(const bf16x4*)(vt + rB + 6144   + cbase);
            o0 = MFMA16(v0, pu.v, o0);
            o1 = MFMA16(v1, pu.v, o1);
            o2 = MFMA16(v2, pu.v, o2);
            o3 = MFMA16(v3, pu.v, o3);
            o4 = MFMA16(one4_.v, pu.v, o4);
        }
        __builtin_amdgcn_s_setprio(0);
#else
        // --- fallback: pack, exchange (16 bpermute + 8 select), K32 PV ---
        unsigned pk[4][2];
#pragma unroll
        for (int mt = 0; mt < 4; ++mt) {
            pk[mt][0] = (unsigned)f2b(p[mt][0]) | ((unsigned)f2b(p[mt][1]) << 16);
            pk[mt][1] = (unsigned)f2b(p[mt][2]) | ((unsigned)f2b(p[mt][3]) << 16);
        }
        __builtin_amdgcn_s_setprio(1);
#pragma unroll
        for (int ks = 0; ks < 2; ++ks) {
            union { unsigned d[4]; bf16x8 v; } pb;
#pragma unroll
            for (int s = 0; s < 4; ++s) {
                int sl = (s >> 1) ? srcL1 : srcL0;
                int u0 = __shfl((int)pk[2*ks    ][s & 1], sl, 64);
                int u1 = __shfl((int)pk[2*ks + 1][s & 1], sl, 64);
                pb.d[s] = (q >> 1) ? (unsigned)u1 : (unsigned)u0;
            }
            const int fk = ks ? f1 : f0;
            bf16x8 v0 = *(const bf16x8*)(vt + rB          + fk);
            bf16x8 v1 = *(const bf16x8*)(vt + rB + 2048   + fk);
            bf16x8 v2 = *(const bf16x8*)(vt + rB + 4096   + fk);
            bf16x8 v3 = *(const bf16x8*)(vt + rB + 6144   + fk);
            o0 = MFMA_BF16(v0, pb.v, o0);
            o1 = MFMA_BF16(v1, pb.v, o1);
            o2 = MFMA_BF16(v2, pb.v, o2);
            o3 = MFMA_BF16(v3, pb.v, o3);
            o4 = MFMA_BF16(one_.v, pb.v, o4);
        }
        __builtin_amdgcn_s_setprio(0);
#endif

        __syncthreads();   // drains staging DMA + joins waves
        cur ^= 1;
    }

    // --- epilogue: denominator from ones-row (C row 0, lanes q==0) ---
    float lsum = __shfl(o4[0], l15, 64);
    float inv = 1.0f / lsum;
#pragma unroll
    for (int r = 0; r < 4; ++r) {
        Os[w][l15][ 0 + q*4 + r] = f2b(o0[r] * inv);
        Os[w][l15][16 + q*4 + r] = f2b(o1[r] * inv);
        Os[w][l15][32 + q*4 + r] = f2b(o2[r] * inv);
        Os[w][l15][48 + q*4 + r] = f2b(o3[r] * inv);
    }
    __syncthreads();
    int rr = lane >> 2, cc = lane & 3;
    uint4 a0 = *(const uint4*)&Os[w][rr][cc*16];
    uint4 a1 = *(const uint4*)&Os[w][rr][cc*16 + 8];
    size_t orow = ((size_t)b*2048 + i0 + w*16 + rr)*768 + h*64 + cc*16;
    *(uint4*)(attnout + orow)     = a0;
    *(uint4*)(attnout + orow + 8) = a1;
}

extern "C" void kernel_launch(void* const* d_in, const int* in_sizes, int n_in,
                              void* d_out, int out_size, void* d_ws, size_t ws_size,
                              hipStream_t stream) {
    (void)in_sizes; (void)n_in; (void)out_size; (void)ws_size;
    const float* x      = (const float*)d_in[0];
    const int*   dist   = (const int*)d_in[1];
    const int*   mask   = (const int*)d_in[2];
    const float* qkv_w  = (const float*)d_in[3];
    const float* qkv_b  = (const float*)d_in[4];
    const float* out_w  = (const float*)d_in[5];
    const float* out_b  = (const float*)d_in[6];
    const float* btab   = (const float*)d_in[7];
    float* out = (float*)d_out;

    char* ws = (char*)d_ws;
    size_t off = 0;
    auto alloc = [&](size_t bytes) { void* p = ws + off; off += (bytes + 255) & ~(size_t)255; return p; };
    u16* xb      = (u16*)alloc((size_t)4096*768*2);
    u16* wqkvT   = (u16*)alloc((size_t)2304*768*2);
    u16* woutT   = (u16*)alloc((size_t)768*768*2);
    u16* Qb      = (u16*)alloc((size_t)24*2048*64*2);
    u16* Kb      = (u16*)alloc((size_t)24*2048*64*2);
    u16* Vtp     = (u16*)alloc((size_t)24*2048*64*2);
    u16* attnout = (u16*)alloc((size_t)4096*768*2);
    unsigned char* dist8 = (unsigned char*)alloc((size_t)2*2048*2048);

    prep<<<8192 + 1536 + 432 + 144, 256, 0, stream>>>(
        x, xb, qkv_w, wqkvT, out_w, woutT, dist, (const unsigned*)mask, dist8);
    gemmQKV<<<dim3(18,64), 256, 0, stream>>>(xb, wqkvT, qkv_b, Qb, Kb, Vtp);
    flashAttn<<<dim3(32,12,2), 256, 0, stream>>>(Qb, Kb, Vtp, dist8, btab, attnout);
    gemmOut<<<dim3(12,64), 256, 0, stream>>>(attnout, woutT, out_b, out);
}

// Round 13
// 220.088 us; speedup vs baseline: 1.0570x; 1.0570x over previous
//
#include <hip/hip_runtime.h>
#include <hip/hip_bf16.h>

typedef unsigned short u16;
typedef __attribute__((ext_vector_type(8))) short bf16x8;
typedef __attribute__((ext_vector_type(4))) short bf16x4;
typedef __attribute__((ext_vector_type(4))) float f32x4;

#define MFMA_BF16(a,b,c) __builtin_amdgcn_mfma_f32_16x16x32_bf16((a),(b),(c),0,0,0)
#define LOG2E 1.4426950408889634f

// K=16 bf16 MFMA: B-frag layout B[k=q*4+r][col=l15] == our P C-layout, so PV
// needs NO cross-lane exchange. Guarded: fall back to K32+bpermute if absent.
#if __has_builtin(__builtin_amdgcn_mfma_f32_16x16x16bf16_1k)
#define MFMA16(a,b,c) __builtin_amdgcn_mfma_f32_16x16x16bf16_1k((a),(b),(c),0,0,0)
#define HAVE_MFMA16 1
#elif __has_builtin(__builtin_amdgcn_mfma_f32_16x16x16_bf16)
#define MFMA16(a,b,c) __builtin_amdgcn_mfma_f32_16x16x16_bf16((a),(b),(c),0,0,0)
#define HAVE_MFMA16 1
#else
#define HAVE_MFMA16 0
#endif

__device__ __forceinline__ u16 f2b(float f) {
    __hip_bfloat16 h = __float2bfloat16(f);
    u16 u; __builtin_memcpy(&u, &h, 2); return u;
}
__device__ __forceinline__ f32x4 zero4() { f32x4 z = {0.f,0.f,0.f,0.f}; return z; }

// async global->LDS, 16B per lane. LDS dest = wave-uniform base + lane*16.
__device__ __forceinline__ void gl_lds16(const u16* g, u16* l) {
    __builtin_amdgcn_global_load_lds(
        (const __attribute__((address_space(1))) unsigned int*)g,
        (__attribute__((address_space(3))) unsigned int*)l,
        16, 0, 0);
}

// ------ fused preprocessing: packDist(+mask detect) | convX | convTW x2 ------
__global__ __launch_bounds__(256)
void prep(const float* __restrict__ x, u16* __restrict__ xb,
          const float* __restrict__ qkv_w, u16* __restrict__ wqkvT,
          const float* __restrict__ out_w, u16* __restrict__ woutT,
          const int* __restrict__ dist, const unsigned* __restrict__ mask,
          unsigned char* __restrict__ dist8) {
    __shared__ __align__(16) u16 T[64][68];
    __shared__ int sB, sH, sF;
    const int bid = blockIdx.x;
    const int tid = threadIdx.x;
    if (bid < 8192) {
        // ---- packDist: dist int32 -> u8 clipped [0,31]; masked (b,j) -> 32 ----
        if (tid == 0) { sB = 0; sH = 0; sF = 0; }
        __syncthreads();
        int lb = 0, lh = 0, lf = 0;
#pragma unroll
        for (int i = 0; i < 4; ++i) {
            unsigned v = mask[tid + i * 256];          // first 4KB: safe under all encodings
            if (v == 0x3f800000u) { lf = 1; }
            else if (v > 1u) {
                unsigned b0 = v & 0xffu, b1 = (v >> 8) & 0xffu, b2 = (v >> 16) & 0xffu, b3 = v >> 24;
                bool bytesOK = (b0 <= 1u) && (b1 <= 1u) && (b2 <= 1u) && (b3 <= 1u);
                unsigned h0 = v & 0xffffu, h1 = v >> 16;
                bool halfOK = (h0 == 0u || h0 == 0x3f80u) && (h1 == 0u || h1 == 0x3f80u);
                if (bytesOK) lb = 1; else if (halfOK) lh = 1;
            }
        }
        if (lb) atomicOr(&sB, 1);
        if (lh) atomicOr(&sH, 1);
        if (lf) atomicOr(&sF, 1);
        __syncthreads();
        int mode = sH ? 3 : (sB ? 1 : (sF ? 2 : 0));
        size_t i = ((size_t)bid * 256 + tid) * 4;
        int4 v = *(const int4*)(dist + i);
        int b = (int)(i >> 22), j = (int)(i & 2047);   // j multiple of 4, no row crossing
        int base = b * 2048 + j;
        int mk0, mk1, mk2, mk3;
        if (mode == 0) {
            int4 mv = *(const int4*)((const int*)mask + base);
            mk0 = mv.x != 0; mk1 = mv.y != 0; mk2 = mv.z != 0; mk3 = mv.w != 0;
        } else if (mode == 1) {
            const unsigned char* m8 = (const unsigned char*)mask;
            mk0 = m8[base] != 0; mk1 = m8[base+1] != 0; mk2 = m8[base+2] != 0; mk3 = m8[base+3] != 0;
        } else if (mode == 2) {
            float4 mv = *(const float4*)((const float*)mask + base);
            mk0 = mv.x != 0.f; mk1 = mv.y != 0.f; mk2 = mv.z != 0.f; mk3 = mv.w != 0.f;
        } else {
            const u16* mh = (const u16*)mask;
            mk0 = mh[base] != 0; mk1 = mh[base+1] != 0; mk2 = mh[base+2] != 0; mk3 = mh[base+3] != 0;
        }
        uchar4 o;
        o.x = mk0 ? 32 : (unsigned char)min(max(v.x, 0), 31);
        o.y = mk1 ? 32 : (unsigned char)min(max(v.y, 0), 31);
        o.z = mk2 ? 32 : (unsigned char)min(max(v.z, 0), 31);
        o.w = mk3 ? 32 : (unsigned char)min(max(v.w, 0), 31);
        *(uchar4*)(dist8 + i) = o;
    } else if (bid < 8192 + 1536) {
        // ---- convX: x f32 -> bf16, 8 elems/thread ----
        size_t i = ((size_t)(bid - 8192) * 256 + tid) * 8;
        float4 a = *(const float4*)(x + i);
        float4 b = *(const float4*)(x + i + 4);
        union { u16 s[8]; uint4 v; } u;
        u.s[0]=f2b(a.x); u.s[1]=f2b(a.y); u.s[2]=f2b(a.z); u.s[3]=f2b(a.w);
        u.s[4]=f2b(b.x); u.s[5]=f2b(b.y); u.s[6]=f2b(b.z); u.s[7]=f2b(b.w);
        *(uint4*)(xb + i) = u.v;
    } else {
        // ---- convTW: weight [768][C] f32 -> [C][768] bf16 transpose+convert ----
        const float* in; u16* out; int C, c0, k0;
        if (bid < 8192 + 1536 + 432) {
            int s = bid - (8192 + 1536);
            in = qkv_w; out = wqkvT; C = 2304;
            c0 = (s % 36) * 64; k0 = (s / 36) * 64;
        } else {
            int s = bid - (8192 + 1536 + 432);
            in = out_w; out = woutT; C = 768;
            c0 = (s % 12) * 64; k0 = (s / 12) * 64;
        }
#pragma unroll
        for (int i = 0; i < 4; ++i) {
            int id = tid + i * 256;
            int row = id >> 4, ch = id & 15;
            float4 v = *(const float4*)(in + (size_t)(k0 + row) * C + c0 + ch * 4);
            T[row][ch*4+0] = f2b(v.x); T[row][ch*4+1] = f2b(v.y);
            T[row][ch*4+2] = f2b(v.z); T[row][ch*4+3] = f2b(v.w);
        }
        __syncthreads();
#pragma unroll
        for (int i = 0; i < 2; ++i) {
            int id = tid + i * 256;
            int c = id >> 3, ch = id & 7;
            union { u16 s[8]; uint4 v; } u;
#pragma unroll
            for (int jj = 0; jj < 8; ++jj) u.s[jj] = T[ch*8+jj][c];
            *(uint4*)(out + (size_t)(c0 + c) * 768 + k0 + ch * 8) = u.v;
        }
    }
}

// ------ QKV GEMM: 128x128 tile (R11 panel economics) + vectorized epilogue ------
// R12 lesson: 64x128 tiles doubled B-panel traffic (+113MB ~ +18us). Revert to
// 128x128 (576 blocks), keep R12's good idea: which = n0/768 is block-uniform
// (128 | 768); Q/K bounce acc -> Ls (aliasing the dead As/Bs staging LDS, so
// LDS stays 32KB) and emit 8 coalesced uint4 stores/thread instead of 64
// scalar 2B stores/lane. V keeps proven direct 8B transposed stores.
__global__ __launch_bounds__(256)
void gemmQKV(const u16* __restrict__ A, const u16* __restrict__ Bt,
             const float* __restrict__ bias,
             u16* __restrict__ qO, u16* __restrict__ kO, u16* __restrict__ vO) {
    __shared__ __align__(16) u16 shmem[16384];   // 32KB: As[2][4096] | Bs[2][4096]; aliased as Ls[16384] post-loop
    const int K = 768;
    const int tid = threadIdx.x;
    const int lane = tid & 63, w = tid >> 6;
    const int wm = w >> 1, wn = w & 1;
    const int l15 = lane & 15, q = lane >> 4;
    const int m0 = blockIdx.y * 128, n0 = blockIdx.x * 128;
    // staging (R10-proven): wave w covers rows [w*32, w*32+32), 2 calls x 16 rows
    const int stRow = lane >> 2;
    const int stChunk = (lane & 3) ^ ((lane >> 3) & 3);
    const u16* Ag = A + (size_t)(m0 + w*32 + stRow) * K + stChunk * 8;
    const u16* Bg = Bt + (size_t)(n0 + w*32 + stRow) * K + stChunk * 8;
    const int fA = (q ^ ((l15 >> 1) & 3)) * 8;   // read-side chunk swizzle

    f32x4 acc[4][4];
#pragma unroll
    for (int i=0;i<4;++i)
#pragma unroll
        for (int j=0;j<4;++j) acc[i][j] = zero4();

    // prologue: stage kt=0 into buf 0
#pragma unroll
    for (int c = 0; c < 2; ++c) {
        gl_lds16(Ag + (size_t)(c*16) * K, shmem + w*32*32 + c*16*32);
        gl_lds16(Bg + (size_t)(c*16) * K, shmem + 8192 + w*32*32 + c*16*32);
    }
    __syncthreads();

    int cur = 0;
    for (int kt = 0; kt < 24; ++kt) {
        if (kt < 23) {
            const int ko = (kt + 1) * 32;
            u16* dA = shmem + (cur^1)*4096 + w*32*32;
            u16* dB = shmem + 8192 + (cur^1)*4096 + w*32*32;
#pragma unroll
            for (int c = 0; c < 2; ++c) {
                gl_lds16(Ag + (size_t)(c*16) * K + ko, dA + c*16*32);
                gl_lds16(Bg + (size_t)(c*16) * K + ko, dB + c*16*32);
            }
        }
        const u16* as = shmem + cur*4096;
        const u16* bs = shmem + 8192 + cur*4096;
        bf16x8 af[4], bfr[4];
#pragma unroll
        for (int mt=0; mt<4; ++mt) af[mt]  = *(const bf16x8*)(as + (wm*64+mt*16+l15)*32 + fA);
#pragma unroll
        for (int nt=0; nt<4; ++nt) bfr[nt] = *(const bf16x8*)(bs + (wn*64+nt*16+l15)*32 + fA);
#pragma unroll
        for (int mt=0; mt<4; ++mt)
#pragma unroll
            for (int nt=0; nt<4; ++nt)
                acc[mt][nt] = MFMA_BF16(af[mt], bfr[nt], acc[mt][nt]);
        __syncthreads();
        cur ^= 1;
    }

    const int which = n0 / 768;                  // block-uniform (128 | 768)
    const int b = m0 >> 11, tokB = m0 & 2047;
    if (which == 2) {
        // V: direct transposed 8B stores (proven)
#pragma unroll
        for (int mt=0; mt<4; ++mt) {
#pragma unroll
            for (int nt=0; nt<4; ++nt) {
                int n = n0 + wn*64 + nt*16 + l15;
                int rem = n - 1536;
                int hh = rem >> 6, hd = rem & 63;
                float bv = bias[n];
                int tok0 = tokB + wm*64 + mt*16 + q*4;
                union { u16 s4[4]; unsigned long long u; } pv;
#pragma unroll
                for (int r=0; r<4; ++r) pv.s4[r] = f2b(acc[mt][nt][r] + bv);
                *(unsigned long long*)(vO + ((size_t)(b*12 + hh)*64 + hd)*2048 + tok0) = pv.u;
            }
        }
    } else {
        // Q/K: bounce acc -> Ls (aliases dead staging LDS), coalesced uint4 stores
        const float sc = (which == 0) ? (0.125f * LOG2E) : 1.0f;
        u16* Ls = shmem;
#pragma unroll
        for (int mt=0; mt<4; ++mt) {
#pragma unroll
            for (int nt=0; nt<4; ++nt) {
                int col = wn*64 + nt*16 + l15;
                float bv = bias[n0 + col];
#pragma unroll
                for (int r=0; r<4; ++r)
                    Ls[(wm*64 + mt*16 + q*4 + r)*128 + col] = f2b((acc[mt][nt][r] + bv) * sc);
            }
        }
        __syncthreads();
        u16* dst = (which == 0) ? qO : kO;
        const int h0 = (n0 - which*768) >> 6;    // 2 heads per 128-wide tile
#pragma unroll
        for (int k = 0; k < 8; ++k) {
            int idx = k*256 + tid;               // 2048 uint4 total
            int row = idx >> 4, rem = idx & 15;
            int hh = rem >> 3, c = rem & 7;
            uint4 v = *(const uint4*)(Ls + row*128 + hh*64 + c*8);
            *(uint4*)(dst + ((size_t)(b*12 + h0 + hh)*2048 + tokB + row)*64 + c*8) = v;
        }
    }
}

// ------ output GEMM: 64x64 tiles, grid (12,64)=768 blocks = 3 blocks/CU ------
__global__ __launch_bounds__(256)
void gemmOut(const u16* __restrict__ A, const u16* __restrict__ Bt,
             const float* __restrict__ bias, float* __restrict__ fO) {
    __shared__ __align__(16) u16 As[2][64*32];
    __shared__ __align__(16) u16 Bs[2][64*32];
    const int K = 768;
    const int tid = threadIdx.x;
    const int lane = tid & 63, w = tid >> 6;
    const int l15 = lane & 15, q = lane >> 4;
    const int m0 = blockIdx.y * 64, n0 = blockIdx.x * 64;
    const int stRow = tid >> 2;                        // 0..63
    const int stChunk = (tid & 3) ^ ((tid >> 3) & 3);  // XOR by (row>>1)&3
    const u16* Ag = A + (size_t)(m0 + stRow) * K + stChunk * 8;
    const u16* Bg = Bt + (size_t)(n0 + stRow) * K + stChunk * 8;
    const int fA = (q ^ ((l15 >> 1) & 3)) * 8;

    f32x4 acc[4];
#pragma unroll
    for (int i=0;i<4;++i) acc[i] = zero4();

    gl_lds16(Ag, &As[0][0] + w*512);
    gl_lds16(Bg, &Bs[0][0] + w*512);
    __syncthreads();

    int cur = 0;
    for (int kt = 0; kt < 24; ++kt) {
        if (kt < 23) {
            const int ko = (kt + 1) * 32;
            gl_lds16(Ag + ko, &As[cur^1][0] + w*512);
            gl_lds16(Bg + ko, &Bs[cur^1][0] + w*512);
        }
        const u16* as = &As[cur][0];
        const u16* bs = &Bs[cur][0];
        bf16x8 af = *(const bf16x8*)(as + (w*16 + l15)*32 + fA);
        bf16x8 bfr[4];
#pragma unroll
        for (int nt=0; nt<4; ++nt) bfr[nt] = *(const bf16x8*)(bs + (nt*16+l15)*32 + fA);
#pragma unroll
        for (int nt=0; nt<4; ++nt) acc[nt] = MFMA_BF16(af, bfr[nt], acc[nt]);
        __syncthreads();
        cur ^= 1;
    }

#pragma unroll
    for (int nt=0; nt<4; ++nt) {
        int n = n0 + nt*16 + l15;
        float bv = bias[n];
#pragma unroll
        for (int r=0; r<4; ++r) {
            int m = m0 + w*16 + q*4 + r;
            fO[(size_t)m*768 + n] = acc[nt][r] + bv;
        }
    }
}

// ------ fused flash attention: LDS-staged K/V/dist, single-pass, K16-MFMA PV ------
// (byte-identical to round 12's 82.2us kernel: T13 threshold defer-max THR=8)
__global__ __launch_bounds__(256)
void flashAttn(const u16* __restrict__ Qb, const u16* __restrict__ Kb,
               const u16* __restrict__ Vt, const unsigned char* __restrict__ dist8,
               const float* __restrict__ btg, u16* __restrict__ attnout) {
    __shared__ float bt[33];
    __shared__ __align__(16) u16 KT[2][4096];   // [buf][64 j][64 d] swizzled
    __shared__ __align__(16) u16 VT[2][4096];   // [buf][64 d][64 j] swizzled
    __shared__ __align__(16) u16 DT[2][2048];   // [buf][64 i][64 j] u8, swizzled
    __shared__ __align__(16) u16 Os[4][16][72];
    const int tid = threadIdx.x;
    const int lane = tid & 63, w = tid >> 6;
    const int l15 = lane & 15, q = lane >> 4;
    // --- XCD-locality remap (bijective on [0,768)) ---
    const int wg = blockIdx.x + 32 * (blockIdx.y + 12 * blockIdx.z);
    const int xcd = wg & 7, slot = wg >> 3;
    const int g = ((slot >> 5) << 3) + xcd;            // group = (b,h), [0,24)
    const int i0 = (slot & 31) * 64;                   // i-block within group
    const int b = g / 12, h = g - b * 12;
    const int bh = g;
    const float NEG_INF = -__builtin_inff();
    if (tid < 33) bt[tid] = (tid == 32) ? NEG_INF : btg[tid*12 + h] * LOG2E;

    const int iRow = i0 + w*16 + l15;
    const u16* Qp = Qb + ((size_t)bh*2048 + iRow)*64;
    bf16x8 qB0 = *(const bf16x8*)(Qp + q*8);
    bf16x8 qB1 = *(const bf16x8*)(Qp + 32 + q*8);
#if !HAVE_MFMA16
    const int srcL0 = ((2*q)   & 3)*16 + l15;
    const int srcL1 = ((2*q+1) & 3)*16 + l15;
    union { unsigned u4[4]; bf16x8 v; } one_;
    { unsigned oc = (l15 == 0) ? 0x3F803F80u : 0u;
      one_.u4[0]=oc; one_.u4[1]=oc; one_.u4[2]=oc; one_.u4[3]=oc; }
#else
    union { unsigned u2[2]; bf16x4 v; } one4_;
    { unsigned oc = (l15 == 0) ? 0x3F803F80u : 0u;
      one4_.u2[0]=oc; one4_.u2[1]=oc; }
#endif

    // --- staging geometry: LDS linear dest, XOR-swizzled source ---
    const int stRow = w*16 + (lane >> 3);                       // K/V: + c*8
    const int stCol = (((lane & 7) ^ (lane >> 3)) << 4);        // K/V 16B chunk
    const int dRow = w*16 + (lane >> 2);                        // dist: 64 rows
    const int dCol = ((lane & 3) ^ ((lane >> 3) & 3)) << 4;     // dist 16B chunk
    const char* kgB = (const char*)Kb + (size_t)bh*2048*128;    // [tok][64d*2B]
    const char* vgB = (const char*)Vt + (size_t)bh*64*4096;     // [d][2048tok*2B]
    const unsigned char* dgB = dist8 + (size_t)(b*2048 + i0)*2048;
    const int swz = (l15 & 7) << 4;
    const int f0 = (q*16)      ^ swz;
    const int f1 = (q*16 + 64) ^ swz;
    const int rB = l15 * 128;
    const int rD = (w*16 + l15) * 64;                           // dist row base
    const int dsw = (l15 >> 1) & 3;                             // dist read swizzle

    // prologue: stage tile 0 into buf 0
    {
        u16* kd = &KT[0][0] + w*1024;
        u16* vd = &VT[0][0] + w*1024;
#pragma unroll
        for (int c = 0; c < 2; ++c) {
            int row = stRow + c*8;
            gl_lds16((const u16*)(kgB + (size_t)row*128 + stCol),  kd + c*512);
            gl_lds16((const u16*)(vgB + (size_t)row*4096 + stCol), vd + c*512);
        }
        gl_lds16((const u16*)(dgB + (size_t)dRow*2048 + dCol),
                 (u16*)((char*)&DT[0][0] + w*1024));
    }
    __syncthreads();

    f32x4 o0 = zero4(), o1 = zero4(), o2 = zero4(), o3 = zero4(), o4 = zero4();
    float mI = NEG_INF;
    int cur = 0;

    for (int jt = 0; jt < 32; ++jt) {
        const int j0 = jt * 64;
        // --- issue next tile's DMA first (hides under compute) ---
        if (jt < 31) {
            const int j0n = j0 + 64;
            u16* kd = &KT[cur^1][0] + w*1024;
            u16* vd = &VT[cur^1][0] + w*1024;
#pragma unroll
            for (int c = 0; c < 2; ++c) {
                int row = stRow + c*8;
                gl_lds16((const u16*)(kgB + (size_t)(j0n + row)*128 + stCol),          kd + c*512);
                gl_lds16((const u16*)(vgB + (size_t)row*4096 + (size_t)j0n*2 + stCol), vd + c*512);
            }
            gl_lds16((const u16*)(dgB + (size_t)dRow*2048 + j0n + dCol),
                     (u16*)((char*)&DT[cur^1][0] + w*1024));
        }
        // dist values from LDS (swizzled)
        const char* dt = (const char*)&DT[cur][0];
        unsigned dv4[4];
#pragma unroll
        for (int mt = 0; mt < 4; ++mt)
            dv4[mt] = *(const unsigned*)(dt + rD + ((mt ^ dsw) << 4) + q*4);

        // --- S^T = K·Q^T from LDS ---
        const char* kt = (const char*)&KT[cur][0];
        f32x4 s0 = zero4(), s1 = zero4(), s2 = zero4(), s3 = zero4();
        {
            bf16x8 k00 = *(const bf16x8*)(kt + rB          + f0);
            bf16x8 k01 = *(const bf16x8*)(kt + rB          + f1);
            bf16x8 k10 = *(const bf16x8*)(kt + rB + 2048   + f0);
            bf16x8 k11 = *(const bf16x8*)(kt + rB + 2048   + f1);
            bf16x8 k20 = *(const bf16x8*)(kt + rB + 4096   + f0);
            bf16x8 k21 = *(const bf16x8*)(kt + rB + 4096   + f1);
            bf16x8 k30 = *(const bf16x8*)(kt + rB + 6144   + f0);
            bf16x8 k31 = *(const bf16x8*)(kt + rB + 6144   + f1);
            __builtin_amdgcn_s_setprio(1);
            s0 = MFMA_BF16(k00, qB0, s0); s0 = MFMA_BF16(k01, qB1, s0);
            s1 = MFMA_BF16(k10, qB0, s1); s1 = MFMA_BF16(k11, qB1, s1);
            s2 = MFMA_BF16(k20, qB0, s2); s2 = MFMA_BF16(k21, qB1, s2);
            s3 = MFMA_BF16(k30, qB0, s3); s3 = MFMA_BF16(k31, qB1, s3);
            __builtin_amdgcn_s_setprio(0);
        }

        // --- bias gather applies mask too (dd==32 -> -inf) ---
        float sv[4][4];
#pragma unroll
        for (int mt = 0; mt < 4; ++mt) {
            const f32x4 sm = mt==0 ? s0 : (mt==1 ? s1 : (mt==2 ? s2 : s3));
            const unsigned d4 = dv4[mt];
#pragma unroll
            for (int r = 0; r < 4; ++r) {
                int dd = (d4 >> (r*8)) & 255;
                sv[mt][r] = sm[r] + bt[dd];
            }
        }

        // --- online max (tree + 2 cross-quad shfl) + THRESHOLD defer-rescale ---
        float t0 = fmaxf(fmaxf(sv[0][0], sv[0][1]), fmaxf(sv[0][2], sv[0][3]));
        float t1 = fmaxf(fmaxf(sv[1][0], sv[1][1]), fmaxf(sv[1][2], sv[1][3]));
        float t2 = fmaxf(fmaxf(sv[2][0], sv[2][1]), fmaxf(sv[2][2], sv[2][3]));
        float t3 = fmaxf(fmaxf(sv[3][0], sv[3][1]), fmaxf(sv[3][2], sv[3][3]));
        float rm = fmaxf(fmaxf(t0, t1), fmaxf(t2, t3));
        rm = fmaxf(rm, __shfl_xor(rm, 16, 64));
        rm = fmaxf(rm, __shfl_xor(rm, 32, 64));
        if (!__all(rm <= mI + 8.0f)) {               // T13: P bounded by 2^8
            float mn = fmaxf(mI, rm);
            float al = exp2f(mI - mn);
            mI = mn;
#pragma unroll
            for (int r = 0; r < 4; ++r) { o0[r] *= al; o1[r] *= al; o2[r] *= al; o3[r] *= al; }
            o4[0] *= al;
        }
        float p[4][4];
#pragma unroll
        for (int mt = 0; mt < 4; ++mt)
#pragma unroll
            for (int r = 0; r < 4; ++r) p[mt][r] = exp2f(sv[mt][r] - mI);

        const char* vt = (const char*)&VT[cur][0];
#if HAVE_MFMA16
        // --- pack P (C-layout == K16 B-frag layout) and PV, no exchange ---
        __builtin_amdgcn_s_setprio(1);
#pragma unroll
        for (int mt = 0; mt < 4; ++mt) {
            union { unsigned d[2]; bf16x4 v; } pu;
            pu.d[0] = (unsigned)f2b(p[mt][0]) | ((unsigned)f2b(p[mt][1]) << 16);
            pu.d[1] = (unsigned)f2b(p[mt][2]) | ((unsigned)f2b(p[mt][3]) << 16);
            const int cbase = (((mt*2 + (q>>1)) ^ (l15 & 7)) << 4) + (q & 1)*8;
            bf16x4 v0 = *(const bf16x4*)(vt + rB          + cbase);
            bf16x4 v1 = *(const bf16x4*)(vt + rB + 2048   + cbase);
            bf16x4 v2 = *(const bf16x4*)(vt + rB + 4096   + cbase);
            bf16x4 v3 = *(const bf16x4*)(vt + rB + 6144   + cbase);
            o0 = MFMA16(v0, pu.v, o0);
            o1 = MFMA16(v1, pu.v, o1);
            o2 = MFMA16(v2, pu.v, o2);
            o3 = MFMA16(v3, pu.v, o3);
            o4 = MFMA16(one4_.v, pu.v, o4);
        }
        __builtin_amdgcn_s_setprio(0);
#else
        // --- fallback: pack, exchange (16 bpermute + 8 select), K32 PV ---
        unsigned pk[4][2];
#pragma unroll
        for (int mt = 0; mt < 4; ++mt) {
            pk[mt][0] = (unsigned)f2b(p[mt][0]) | ((unsigned)f2b(p[mt][1]) << 16);
            pk[mt][1] = (unsigned)f2b(p[mt][2]) | ((unsigned)f2b(p[mt][3]) << 16);
        }
        __builtin_amdgcn_s_setprio(1);
#pragma unroll
        for (int ks = 0; ks < 2; ++ks) {
            union { unsigned d[4]; bf16x8 v; } pb;
#pragma unroll
            for (int s = 0; s < 4; ++s) {
                int sl = (s >> 1) ? srcL1 : srcL0;
                int u0 = __shfl((int)pk[2*ks    ][s & 1], sl, 64);
                int u1 = __shfl((int)pk[2*ks + 1][s & 1], sl, 64);
                pb.d[s] = (q >> 1) ? (unsigned)u1 : (unsigned)u0;
            }
            const int fk = ks ? f1 : f0;
            bf16x8 v0 = *(const bf16x8*)(vt + rB          + fk);
            bf16x8 v1 = *(const bf16x8*)(vt + rB + 2048   + fk);
            bf16x8 v2 = *(const bf16x8*)(vt + rB + 4096   + fk);
            bf16x8 v3 = *(const bf16x8*)(vt + rB + 6144   + fk);
            o0 = MFMA_BF16(v0, pb.v, o0);
            o1 = MFMA_BF16(v1, pb.v, o1);
            o2 = MFMA_BF16(v2, pb.v, o2);
            o3 = MFMA_BF16(v3, pb.v, o3);
            o4 = MFMA_BF16(one_.v, pb.v, o4);
        }
        __builtin_amdgcn_s_setprio(0);
#endif

        __syncthreads();   // drains staging DMA + joins waves
        cur ^= 1;
    }

    // --- epilogue: denominator from ones-row (C row 0, lanes q==0) ---
    float lsum = __shfl(o4[0], l15, 64);
    float inv = 1.0f / lsum;
#pragma unroll
    for (int r = 0; r < 4; ++r) {
        Os[w][l15][ 0 + q*4 + r] = f2b(o0[r] * inv);
        Os[w][l15][16 + q*4 + r] = f2b(o1[r] * inv);
        Os[w][l15][32 + q*4 + r] = f2b(o2[r] * inv);
        Os[w][l15][48 + q*4 + r] = f2b(o3[r] * inv);
    }
    __syncthreads();
    int rr = lane >> 2, cc = lane & 3;
    uint4 a0 = *(const uint4*)&Os[w][rr][cc*16];
    uint4 a1 = *(const uint4*)&Os[w][rr][cc*16 + 8];
    size_t orow = ((size_t)b*2048 + i0 + w*16 + rr)*768 + h*64 + cc*16;
    *(uint4*)(attnout + orow)     = a0;
    *(uint4*)(attnout + orow + 8) = a1;
}

extern "C" void kernel_launch(void* const* d_in, const int* in_sizes, int n_in,
                              void* d_out, int out_size, void* d_ws, size_t ws_size,
                              hipStream_t stream) {
    (void)in_sizes; (void)n_in; (void)out_size; (void)ws_size;
    const float* x      = (const float*)d_in[0];
    const int*   dist   = (const int*)d_in[1];
    const int*   mask   = (const int*)d_in[2];
    const float* qkv_w  = (const float*)d_in[3];
    const float* qkv_b  = (const float*)d_in[4];
    const float* out_w  = (const float*)d_in[5];
    const float* out_b  = (const float*)d_in[6];
    const float* btab   = (const float*)d_in[7];
    float* out = (float*)d_out;

    char* ws = (char*)d_ws;
    size_t off = 0;
    auto alloc = [&](size_t bytes) { void* p = ws + off; off += (bytes + 255) & ~(size_t)255; return p; };
    u16* xb      = (u16*)alloc((size_t)4096*768*2);
    u16* wqkvT   = (u16*)alloc((size_t)2304*768*2);
    u16* woutT   = (u16*)alloc((size_t)768*768*2);
    u16* Qb      = (u16*)alloc((size_t)24*2048*64*2);
    u16* Kb      = (u16*)alloc((size_t)24*2048*64*2);
    u16* Vtp     = (u16*)alloc((size_t)24*2048*64*2);
    u16* attnout = (u16*)alloc((size_t)4096*768*2);
    unsigned char* dist8 = (unsigned char*)alloc((size_t)2*2048*2048);

    prep<<<8192 + 1536 + 432 + 144, 256, 0, stream>>>(
        x, xb, qkv_w, wqkvT, out_w, woutT, dist, (const unsigned*)mask, dist8);
    gemmQKV<<<dim3(18,32), 256, 0, stream>>>(xb, wqkvT, qkv_b, Qb, Kb, Vtp);
    flashAttn<<<dim3(32,12,2), 256, 0, stream>>>(Qb, Kb, Vtp, dist8, btab, attnout);
    gemmOut<<<dim3(12,64), 256, 0, stream>>>(attnout, woutT, out_b, out);
}

// Round 14
// 214.417 us; speedup vs baseline: 1.0849x; 1.0265x over previous
//
#include <hip/hip_runtime.h>
#include <hip/hip_bf16.h>

typedef unsigned short u16;
typedef __attribute__((ext_vector_type(8))) short bf16x8;
typedef __attribute__((ext_vector_type(4))) short bf16x4;
typedef __attribute__((ext_vector_type(4))) float f32x4;

#define MFMA_BF16(a,b,c) __builtin_amdgcn_mfma_f32_16x16x32_bf16((a),(b),(c),0,0,0)
#define LOG2E 1.4426950408889634f

// K=16 bf16 MFMA: B-frag layout B[k=q*4+r][col=l15] == our P C-layout, so PV
// needs NO cross-lane exchange. Guarded: fall back to K32+bpermute if absent.
#if __has_builtin(__builtin_amdgcn_mfma_f32_16x16x16bf16_1k)
#define MFMA16(a,b,c) __builtin_amdgcn_mfma_f32_16x16x16bf16_1k((a),(b),(c),0,0,0)
#define HAVE_MFMA16 1
#elif __has_builtin(__builtin_amdgcn_mfma_f32_16x16x16_bf16)
#define MFMA16(a,b,c) __builtin_amdgcn_mfma_f32_16x16x16_bf16((a),(b),(c),0,0,0)
#define HAVE_MFMA16 1
#else
#define HAVE_MFMA16 0
#endif

__device__ __forceinline__ u16 f2b(float f) {
    __hip_bfloat16 h = __float2bfloat16(f);
    u16 u; __builtin_memcpy(&u, &h, 2); return u;
}
__device__ __forceinline__ f32x4 zero4() { f32x4 z = {0.f,0.f,0.f,0.f}; return z; }

// async global->LDS, 16B per lane. LDS dest = wave-uniform base + lane*16.
__device__ __forceinline__ void gl_lds16(const u16* g, u16* l) {
    __builtin_amdgcn_global_load_lds(
        (const __attribute__((address_space(1))) unsigned int*)g,
        (__attribute__((address_space(3))) unsigned int*)l,
        16, 0, 0);
}

// ------ fused preprocessing: packDist(+mask detect) | convX | convTW x2 ------
// dist8 stores dd*4 (byte offset into the f32 bias table); masked (b,j) -> 128.
__global__ __launch_bounds__(256)
void prep(const float* __restrict__ x, u16* __restrict__ xb,
          const float* __restrict__ qkv_w, u16* __restrict__ wqkvT,
          const float* __restrict__ out_w, u16* __restrict__ woutT,
          const int* __restrict__ dist, const unsigned* __restrict__ mask,
          unsigned char* __restrict__ dist8) {
    __shared__ __align__(16) u16 T[64][68];
    __shared__ int sB, sH, sF;
    const int bid = blockIdx.x;
    const int tid = threadIdx.x;
    if (bid < 8192) {
        // ---- packDist: dist int32 -> u8 (dd*4, clipped); masked -> 128 ----
        if (tid == 0) { sB = 0; sH = 0; sF = 0; }
        __syncthreads();
        int lb = 0, lh = 0, lf = 0;
#pragma unroll
        for (int i = 0; i < 4; ++i) {
            unsigned v = mask[tid + i * 256];          // first 4KB: safe under all encodings
            if (v == 0x3f800000u) { lf = 1; }
            else if (v > 1u) {
                unsigned b0 = v & 0xffu, b1 = (v >> 8) & 0xffu, b2 = (v >> 16) & 0xffu, b3 = v >> 24;
                bool bytesOK = (b0 <= 1u) && (b1 <= 1u) && (b2 <= 1u) && (b3 <= 1u);
                unsigned h0 = v & 0xffffu, h1 = v >> 16;
                bool halfOK = (h0 == 0u || h0 == 0x3f80u) && (h1 == 0u || h1 == 0x3f80u);
                if (bytesOK) lb = 1; else if (halfOK) lh = 1;
            }
        }
        if (lb) atomicOr(&sB, 1);
        if (lh) atomicOr(&sH, 1);
        if (lf) atomicOr(&sF, 1);
        __syncthreads();
        int mode = sH ? 3 : (sB ? 1 : (sF ? 2 : 0));
        size_t i = ((size_t)bid * 256 + tid) * 4;
        int4 v = *(const int4*)(dist + i);
        int b = (int)(i >> 22), j = (int)(i & 2047);   // j multiple of 4, no row crossing
        int base = b * 2048 + j;
        int mk0, mk1, mk2, mk3;
        if (mode == 0) {
            int4 mv = *(const int4*)((const int*)mask + base);
            mk0 = mv.x != 0; mk1 = mv.y != 0; mk2 = mv.z != 0; mk3 = mv.w != 0;
        } else if (mode == 1) {
            const unsigned char* m8 = (const unsigned char*)mask;
            mk0 = m8[base] != 0; mk1 = m8[base+1] != 0; mk2 = m8[base+2] != 0; mk3 = m8[base+3] != 0;
        } else if (mode == 2) {
            float4 mv = *(const float4*)((const float*)mask + base);
            mk0 = mv.x != 0.f; mk1 = mv.y != 0.f; mk2 = mv.z != 0.f; mk3 = mv.w != 0.f;
        } else {
            const u16* mh = (const u16*)mask;
            mk0 = mh[base] != 0; mk1 = mh[base+1] != 0; mk2 = mh[base+2] != 0; mk3 = mh[base+3] != 0;
        }
        uchar4 o;
        o.x = mk0 ? 128 : (unsigned char)(min(max(v.x, 0), 31) * 4);
        o.y = mk1 ? 128 : (unsigned char)(min(max(v.y, 0), 31) * 4);
        o.z = mk2 ? 128 : (unsigned char)(min(max(v.z, 0), 31) * 4);
        o.w = mk3 ? 128 : (unsigned char)(min(max(v.w, 0), 31) * 4);
        *(uchar4*)(dist8 + i) = o;
    } else if (bid < 8192 + 1536) {
        // ---- convX: x f32 -> bf16, 8 elems/thread ----
        size_t i = ((size_t)(bid - 8192) * 256 + tid) * 8;
        float4 a = *(const float4*)(x + i);
        float4 b = *(const float4*)(x + i + 4);
        union { u16 s[8]; uint4 v; } u;
        u.s[0]=f2b(a.x); u.s[1]=f2b(a.y); u.s[2]=f2b(a.z); u.s[3]=f2b(a.w);
        u.s[4]=f2b(b.x); u.s[5]=f2b(b.y); u.s[6]=f2b(b.z); u.s[7]=f2b(b.w);
        *(uint4*)(xb + i) = u.v;
    } else {
        // ---- convTW: weight [768][C] f32 -> [C][768] bf16 transpose+convert ----
        const float* in; u16* out; int C, c0, k0;
        if (bid < 8192 + 1536 + 432) {
            int s = bid - (8192 + 1536);
            in = qkv_w; out = wqkvT; C = 2304;
            c0 = (s % 36) * 64; k0 = (s / 36) * 64;
        } else {
            int s = bid - (8192 + 1536 + 432);
            in = out_w; out = woutT; C = 768;
            c0 = (s % 12) * 64; k0 = (s / 12) * 64;
        }
#pragma unroll
        for (int i = 0; i < 4; ++i) {
            int id = tid + i * 256;
            int row = id >> 4, ch = id & 15;
            float4 v = *(const float4*)(in + (size_t)(k0 + row) * C + c0 + ch * 4);
            T[row][ch*4+0] = f2b(v.x); T[row][ch*4+1] = f2b(v.y);
            T[row][ch*4+2] = f2b(v.z); T[row][ch*4+3] = f2b(v.w);
        }
        __syncthreads();
#pragma unroll
        for (int i = 0; i < 2; ++i) {
            int id = tid + i * 256;
            int c = id >> 3, ch = id & 7;
            union { u16 s[8]; uint4 v; } u;
#pragma unroll
            for (int jj = 0; jj < 8; ++jj) u.s[jj] = T[ch*8+jj][c];
            *(uint4*)(out + (size_t)(c0 + c) * 768 + k0 + ch * 8) = u.v;
        }
    }
}

// ------ QKV GEMM: 128x128 tile + vectorized epilogue + XCD swizzle (T1) ------
// XCD chunk = 72 blocks = 4 m-rows x 18 n: shares 4 A-panels (784KB) + whole
// B (3.5MB) ~ one XCD L2. 576 % 8 == 0 -> bijective.
__global__ __launch_bounds__(256)
void gemmQKV(const u16* __restrict__ A, const u16* __restrict__ Bt,
             const float* __restrict__ bias,
             u16* __restrict__ qO, u16* __restrict__ kO, u16* __restrict__ vO) {
    __shared__ __align__(16) u16 shmem[16384];   // 32KB: As[2][4096] | Bs[2][4096]; aliased as Ls post-loop
    const int K = 768;
    const int tid = threadIdx.x;
    const int lane = tid & 63, w = tid >> 6;
    const int wm = w >> 1, wn = w & 1;
    const int l15 = lane & 15, q = lane >> 4;
    // XCD-locality remap
    const int wg0 = blockIdx.x + 18 * blockIdx.y;
    const int nid = (wg0 & 7) * 72 + (wg0 >> 3);
    const int m0 = (nid / 18) * 128, n0 = (nid % 18) * 128;
    // staging (R10-proven): wave w covers rows [w*32, w*32+32), 2 calls x 16 rows
    const int stRow = lane >> 2;
    const int stChunk = (lane & 3) ^ ((lane >> 3) & 3);
    const u16* Ag = A + (size_t)(m0 + w*32 + stRow) * K + stChunk * 8;
    const u16* Bg = Bt + (size_t)(n0 + w*32 + stRow) * K + stChunk * 8;
    const int fA = (q ^ ((l15 >> 1) & 3)) * 8;   // read-side chunk swizzle

    f32x4 acc[4][4];
#pragma unroll
    for (int i=0;i<4;++i)
#pragma unroll
        for (int j=0;j<4;++j) acc[i][j] = zero4();

    // prologue: stage kt=0 into buf 0
#pragma unroll
    for (int c = 0; c < 2; ++c) {
        gl_lds16(Ag + (size_t)(c*16) * K, shmem + w*32*32 + c*16*32);
        gl_lds16(Bg + (size_t)(c*16) * K, shmem + 8192 + w*32*32 + c*16*32);
    }
    __syncthreads();

    int cur = 0;
    for (int kt = 0; kt < 24; ++kt) {
        if (kt < 23) {
            const int ko = (kt + 1) * 32;
            u16* dA = shmem + (cur^1)*4096 + w*32*32;
            u16* dB = shmem + 8192 + (cur^1)*4096 + w*32*32;
#pragma unroll
            for (int c = 0; c < 2; ++c) {
                gl_lds16(Ag + (size_t)(c*16) * K + ko, dA + c*16*32);
                gl_lds16(Bg + (size_t)(c*16) * K + ko, dB + c*16*32);
            }
        }
        const u16* as = shmem + cur*4096;
        const u16* bs = shmem + 8192 + cur*4096;
        bf16x8 af[4], bfr[4];
#pragma unroll
        for (int mt=0; mt<4; ++mt) af[mt]  = *(const bf16x8*)(as + (wm*64+mt*16+l15)*32 + fA);
#pragma unroll
        for (int nt=0; nt<4; ++nt) bfr[nt] = *(const bf16x8*)(bs + (wn*64+nt*16+l15)*32 + fA);
#pragma unroll
        for (int mt=0; mt<4; ++mt)
#pragma unroll
            for (int nt=0; nt<4; ++nt)
                acc[mt][nt] = MFMA_BF16(af[mt], bfr[nt], acc[mt][nt]);
        __syncthreads();
        cur ^= 1;
    }

    const int which = n0 / 768;                  // block-uniform (128 | 768)
    const int b = m0 >> 11, tokB = m0 & 2047;
    if (which == 2) {
        // V: direct transposed 8B stores (proven)
#pragma unroll
        for (int mt=0; mt<4; ++mt) {
#pragma unroll
            for (int nt=0; nt<4; ++nt) {
                int n = n0 + wn*64 + nt*16 + l15;
                int rem = n - 1536;
                int hh = rem >> 6, hd = rem & 63;
                float bv = bias[n];
                int tok0 = tokB + wm*64 + mt*16 + q*4;
                union { u16 s4[4]; unsigned long long u; } pv;
#pragma unroll
                for (int r=0; r<4; ++r) pv.s4[r] = f2b(acc[mt][nt][r] + bv);
                *(unsigned long long*)(vO + ((size_t)(b*12 + hh)*64 + hd)*2048 + tok0) = pv.u;
            }
        }
    } else {
        // Q/K: bounce acc -> Ls (aliases dead staging LDS), coalesced uint4 stores
        const float sc = (which == 0) ? (0.125f * LOG2E) : 1.0f;
        u16* Ls = shmem;
#pragma unroll
        for (int mt=0; mt<4; ++mt) {
#pragma unroll
            for (int nt=0; nt<4; ++nt) {
                int col = wn*64 + nt*16 + l15;
                float bv = bias[n0 + col];
#pragma unroll
                for (int r=0; r<4; ++r)
                    Ls[(wm*64 + mt*16 + q*4 + r)*128 + col] = f2b((acc[mt][nt][r] + bv) * sc);
            }
        }
        __syncthreads();
        u16* dst = (which == 0) ? qO : kO;
        const int h0 = (n0 - which*768) >> 6;    // 2 heads per 128-wide tile
#pragma unroll
        for (int k = 0; k < 8; ++k) {
            int idx = k*256 + tid;               // 2048 uint4 total
            int row = idx >> 4, rem = idx & 15;
            int hh = rem >> 3, c = rem & 7;
            uint4 v = *(const uint4*)(Ls + row*128 + hh*64 + c*8);
            *(uint4*)(dst + ((size_t)(b*12 + h0 + hh)*2048 + tokB + row)*64 + c*8) = v;
        }
    }
}

// ------ output GEMM: 64x64 tiles + XCD swizzle (chunk 96 = 8m x 12n) ------
__global__ __launch_bounds__(256)
void gemmOut(const u16* __restrict__ A, const u16* __restrict__ Bt,
             const float* __restrict__ bias, float* __restrict__ fO) {
    __shared__ __align__(16) u16 As[2][64*32];
    __shared__ __align__(16) u16 Bs[2][64*32];
    const int K = 768;
    const int tid = threadIdx.x;
    const int lane = tid & 63, w = tid >> 6;
    const int l15 = lane & 15, q = lane >> 4;
    // XCD-locality remap (768 % 8 == 0 -> bijective)
    const int wg0 = blockIdx.x + 12 * blockIdx.y;
    const int nid = (wg0 & 7) * 96 + (wg0 >> 3);
    const int m0 = (nid / 12) * 64, n0 = (nid % 12) * 64;
    const int stRow = tid >> 2;                        // 0..63
    const int stChunk = (tid & 3) ^ ((tid >> 3) & 3);  // XOR by (row>>1)&3
    const u16* Ag = A + (size_t)(m0 + stRow) * K + stChunk * 8;
    const u16* Bg = Bt + (size_t)(n0 + stRow) * K + stChunk * 8;
    const int fA = (q ^ ((l15 >> 1) & 3)) * 8;

    f32x4 acc[4];
#pragma unroll
    for (int i=0;i<4;++i) acc[i] = zero4();

    gl_lds16(Ag, &As[0][0] + w*512);
    gl_lds16(Bg, &Bs[0][0] + w*512);
    __syncthreads();

    int cur = 0;
    for (int kt = 0; kt < 24; ++kt) {
        if (kt < 23) {
            const int ko = (kt + 1) * 32;
            gl_lds16(Ag + ko, &As[cur^1][0] + w*512);
            gl_lds16(Bg + ko, &Bs[cur^1][0] + w*512);
        }
        const u16* as = &As[cur][0];
        const u16* bs = &Bs[cur][0];
        bf16x8 af = *(const bf16x8*)(as + (w*16 + l15)*32 + fA);
        bf16x8 bfr[4];
#pragma unroll
        for (int nt=0; nt<4; ++nt) bfr[nt] = *(const bf16x8*)(bs + (nt*16+l15)*32 + fA);
#pragma unroll
        for (int nt=0; nt<4; ++nt) acc[nt] = MFMA_BF16(af, bfr[nt], acc[nt]);
        __syncthreads();
        cur ^= 1;
    }

#pragma unroll
    for (int nt=0; nt<4; ++nt) {
        int n = n0 + nt*16 + l15;
        float bv = bias[n];
#pragma unroll
        for (int r=0; r<4; ++r) {
            int m = m0 + w*16 + q*4 + r;
            fO[(size_t)m*768 + n] = acc[nt][r] + bv;
        }
    }
}

// ------ fused flash attention: LDS-staged K/V/dist, single-pass, K16-MFMA PV ------
// R14: dist8 now stores dd*4 (direct byte offset into bt) -- bias gather is
// bfe + ds_read, no shift/add per element. Masked entries = 128 -> bt[-inf].
__global__ __launch_bounds__(256)
void flashAttn(const u16* __restrict__ Qb, const u16* __restrict__ Kb,
               const u16* __restrict__ Vt, const unsigned char* __restrict__ dist8,
               const float* __restrict__ btg, u16* __restrict__ attnout) {
    __shared__ float bt[33];
    __shared__ __align__(16) u16 KT[2][4096];   // [buf][64 j][64 d] swizzled
    __shared__ __align__(16) u16 VT[2][4096];   // [buf][64 d][64 j] swizzled
    __shared__ __align__(16) u16 DT[2][2048];   // [buf][64 i][64 j] u8, swizzled
    __shared__ __align__(16) u16 Os[4][16][72];
    const int tid = threadIdx.x;
    const int lane = tid & 63, w = tid >> 6;
    const int l15 = lane & 15, q = lane >> 4;
    // --- XCD-locality remap (bijective on [0,768)) ---
    const int wg = blockIdx.x + 32 * (blockIdx.y + 12 * blockIdx.z);
    const int xcd = wg & 7, slot = wg >> 3;
    const int g = ((slot >> 5) << 3) + xcd;            // group = (b,h), [0,24)
    const int i0 = (slot & 31) * 64;                   // i-block within group
    const int b = g / 12, h = g - b * 12;
    const int bh = g;
    const float NEG_INF = -__builtin_inff();
    if (tid < 33) bt[tid] = (tid == 32) ? NEG_INF : btg[tid*12 + h] * LOG2E;

    const int iRow = i0 + w*16 + l15;
    const u16* Qp = Qb + ((size_t)bh*2048 + iRow)*64;
    bf16x8 qB0 = *(const bf16x8*)(Qp + q*8);
    bf16x8 qB1 = *(const bf16x8*)(Qp + 32 + q*8);
#if !HAVE_MFMA16
    const int srcL0 = ((2*q)   & 3)*16 + l15;
    const int srcL1 = ((2*q+1) & 3)*16 + l15;
    union { unsigned u4[4]; bf16x8 v; } one_;
    { unsigned oc = (l15 == 0) ? 0x3F803F80u : 0u;
      one_.u4[0]=oc; one_.u4[1]=oc; one_.u4[2]=oc; one_.u4[3]=oc; }
#else
    union { unsigned u2[2]; bf16x4 v; } one4_;
    { unsigned oc = (l15 == 0) ? 0x3F803F80u : 0u;
      one4_.u2[0]=oc; one4_.u2[1]=oc; }
#endif

    // --- staging geometry: LDS linear dest, XOR-swizzled source ---
    const int stRow = w*16 + (lane >> 3);                       // K/V: + c*8
    const int stCol = (((lane & 7) ^ (lane >> 3)) << 4);        // K/V 16B chunk
    const int dRow = w*16 + (lane >> 2);                        // dist: 64 rows
    const int dCol = ((lane & 3) ^ ((lane >> 3) & 3)) << 4;     // dist 16B chunk
    const char* kgB = (const char*)Kb + (size_t)bh*2048*128;    // [tok][64d*2B]
    const char* vgB = (const char*)Vt + (size_t)bh*64*4096;     // [d][2048tok*2B]
    const unsigned char* dgB = dist8 + (size_t)(b*2048 + i0)*2048;
    const int swz = (l15 & 7) << 4;
    const int f0 = (q*16)      ^ swz;
    const int f1 = (q*16 + 64) ^ swz;
    const int rB = l15 * 128;
    const int rD = (w*16 + l15) * 64;                           // dist row base
    const int dsw = (l15 >> 1) & 3;                             // dist read swizzle

    // prologue: stage tile 0 into buf 0
    {
        u16* kd = &KT[0][0] + w*1024;
        u16* vd = &VT[0][0] + w*1024;
#pragma unroll
        for (int c = 0; c < 2; ++c) {
            int row = stRow + c*8;
            gl_lds16((const u16*)(kgB + (size_t)row*128 + stCol),  kd + c*512);
            gl_lds16((const u16*)(vgB + (size_t)row*4096 + stCol), vd + c*512);
        }
        gl_lds16((const u16*)(dgB + (size_t)dRow*2048 + dCol),
                 (u16*)((char*)&DT[0][0] + w*1024));
    }
    __syncthreads();

    f32x4 o0 = zero4(), o1 = zero4(), o2 = zero4(), o3 = zero4(), o4 = zero4();
    float mI = NEG_INF;
    int cur = 0;

    for (int jt = 0; jt < 32; ++jt) {
        const int j0 = jt * 64;
        // --- issue next tile's DMA first (hides under compute) ---
        if (jt < 31) {
            const int j0n = j0 + 64;
            u16* kd = &KT[cur^1][0] + w*1024;
            u16* vd = &VT[cur^1][0] + w*1024;
#pragma unroll
            for (int c = 0; c < 2; ++c) {
                int row = stRow + c*8;
                gl_lds16((const u16*)(kgB + (size_t)(j0n + row)*128 + stCol),          kd + c*512);
                gl_lds16((const u16*)(vgB + (size_t)row*4096 + (size_t)j0n*2 + stCol), vd + c*512);
            }
            gl_lds16((const u16*)(dgB + (size_t)dRow*2048 + j0n + dCol),
                     (u16*)((char*)&DT[cur^1][0] + w*1024));
        }
        // dist byte-offsets from LDS (swizzled)
        const char* dt = (const char*)&DT[cur][0];
        unsigned dv4[4];
#pragma unroll
        for (int mt = 0; mt < 4; ++mt)
            dv4[mt] = *(const unsigned*)(dt + rD + ((mt ^ dsw) << 4) + q*4);

        // --- S^T = K·Q^T from LDS ---
        const char* kt = (const char*)&KT[cur][0];
        f32x4 s0 = zero4(), s1 = zero4(), s2 = zero4(), s3 = zero4();
        {
            bf16x8 k00 = *(const bf16x8*)(kt + rB          + f0);
            bf16x8 k01 = *(const bf16x8*)(kt + rB          + f1);
            bf16x8 k10 = *(const bf16x8*)(kt + rB + 2048   + f0);
            bf16x8 k11 = *(const bf16x8*)(kt + rB + 2048   + f1);
            bf16x8 k20 = *(const bf16x8*)(kt + rB + 4096   + f0);
            bf16x8 k21 = *(const bf16x8*)(kt + rB + 4096   + f1);
            bf16x8 k30 = *(const bf16x8*)(kt + rB + 6144   + f0);
            bf16x8 k31 = *(const bf16x8*)(kt + rB + 6144   + f1);
            __builtin_amdgcn_s_setprio(1);
            s0 = MFMA_BF16(k00, qB0, s0); s0 = MFMA_BF16(k01, qB1, s0);
            s1 = MFMA_BF16(k10, qB0, s1); s1 = MFMA_BF16(k11, qB1, s1);
            s2 = MFMA_BF16(k20, qB0, s2); s2 = MFMA_BF16(k21, qB1, s2);
            s3 = MFMA_BF16(k30, qB0, s3); s3 = MFMA_BF16(k31, qB1, s3);
            __builtin_amdgcn_s_setprio(0);
        }

        // --- bias gather (dd = byte offset; 128 -> -inf) applies mask too ---
        float sv[4][4];
#pragma unroll
        for (int mt = 0; mt < 4; ++mt) {
            const f32x4 sm = mt==0 ? s0 : (mt==1 ? s1 : (mt==2 ? s2 : s3));
            const unsigned d4 = dv4[mt];
#pragma unroll
            for (int r = 0; r < 4; ++r) {
                unsigned dd = (d4 >> (r*8)) & 255u;
                float btv = *(const float*)((const char*)bt + dd);
                sv[mt][r] = sm[r] + btv;
            }
        }

        // --- online max (tree + 2 cross-quad shfl) + THRESHOLD defer-rescale ---
        float t0 = fmaxf(fmaxf(sv[0][0], sv[0][1]), fmaxf(sv[0][2], sv[0][3]));
        float t1 = fmaxf(fmaxf(sv[1][0], sv[1][1]), fmaxf(sv[1][2], sv[1][3]));
        float t2 = fmaxf(fmaxf(sv[2][0], sv[2][1]), fmaxf(sv[2][2], sv[2][3]));
        float t3 = fmaxf(fmaxf(sv[3][0], sv[3][1]), fmaxf(sv[3][2], sv[3][3]));
        float rm = fmaxf(fmaxf(t0, t1), fmaxf(t2, t3));
        rm = fmaxf(rm, __shfl_xor(rm, 16, 64));
        rm = fmaxf(rm, __shfl_xor(rm, 32, 64));
        if (!__all(rm <= mI + 8.0f)) {               // T13: P bounded by 2^8
            float mn = fmaxf(mI, rm);
            float al = exp2f(mI - mn);
            mI = mn;
#pragma unroll
            for (int r = 0; r < 4; ++r) { o0[r] *= al; o1[r] *= al; o2[r] *= al; o3[r] *= al; }
            o4[0] *= al;
        }
        float p[4][4];
#pragma unroll
        for (int mt = 0; mt < 4; ++mt)
#pragma unroll
            for (int r = 0; r < 4; ++r) p[mt][r] = exp2f(sv[mt][r] - mI);

        const char* vt = (const char*)&VT[cur][0];
#if HAVE_MFMA16
        // --- pack P (C-layout == K16 B-frag layout) and PV, no exchange ---
        __builtin_amdgcn_s_setprio(1);
#pragma unroll
        for (int mt = 0; mt < 4; ++mt) {
            union { unsigned d[2]; bf16x4 v; } pu;
            pu.d[0] = (unsigned)f2b(p[mt][0]) | ((unsigned)f2b(p[mt][1]) << 16);
            pu.d[1] = (unsigned)f2b(p[mt][2]) | ((unsigned)f2b(p[mt][3]) << 16);
            const int cbase = (((mt*2 + (q>>1)) ^ (l15 & 7)) << 4) + (q & 1)*8;
            bf16x4 v0 = *(const bf16x4*)(vt + rB          + cbase);
            bf16x4 v1 = *(const bf16x4*)(vt + rB + 2048   + cbase);
            bf16x4 v2 = *(const bf16x4*)(vt + rB + 4096   + cbase);
            bf16x4 v3 = *(const bf16x4*)(vt + rB + 6144   + cbase);
            o0 = MFMA16(v0, pu.v, o0);
            o1 = MFMA16(v1, pu.v, o1);
            o2 = MFMA16(v2, pu.v, o2);
            o3 = MFMA16(v3, pu.v, o3);
            o4 = MFMA16(one4_.v, pu.v, o4);
        }
        __builtin_amdgcn_s_setprio(0);
#else
        // --- fallback: pack, exchange (16 bpermute + 8 select), K32 PV ---
        unsigned pk[4][2];
#pragma unroll
        for (int mt = 0; mt < 4; ++mt) {
            pk[mt][0] = (unsigned)f2b(p[mt][0]) | ((unsigned)f2b(p[mt][1]) << 16);
            pk[mt][1] = (unsigned)f2b(p[mt][2]) | ((unsigned)f2b(p[mt][3]) << 16);
        }
        __builtin_amdgcn_s_setprio(1);
#pragma unroll
        for (int ks = 0; ks < 2; ++ks) {
            union { unsigned d[4]; bf16x8 v; } pb;
#pragma unroll
            for (int s = 0; s < 4; ++s) {
                int sl = (s >> 1) ? srcL1 : srcL0;
                int u0 = __shfl((int)pk[2*ks    ][s & 1], sl, 64);
                int u1 = __shfl((int)pk[2*ks + 1][s & 1], sl, 64);
                pb.d[s] = (q >> 1) ? (unsigned)u1 : (unsigned)u0;
            }
            const int fk = ks ? f1 : f0;
            bf16x8 v0 = *(const bf16x8*)(vt + rB          + fk);
            bf16x8 v1 = *(const bf16x8*)(vt + rB + 2048   + fk);
            bf16x8 v2 = *(const bf16x8*)(vt + rB + 4096   + fk);
            bf16x8 v3 = *(const bf16x8*)(vt + rB + 6144   + fk);
            o0 = MFMA_BF16(v0, pb.v, o0);
            o1 = MFMA_BF16(v1, pb.v, o1);
            o2 = MFMA_BF16(v2, pb.v, o2);
            o3 = MFMA_BF16(v3, pb.v, o3);
            o4 = MFMA_BF16(one_.v, pb.v, o4);
        }
        __builtin_amdgcn_s_setprio(0);
#endif

        __syncthreads();   // drains staging DMA + joins waves
        cur ^= 1;
    }

    // --- epilogue: denominator from ones-row (C row 0, lanes q==0) ---
    float lsum = __shfl(o4[0], l15, 64);
    float inv = 1.0f / lsum;
#pragma unroll
    for (int r = 0; r < 4; ++r) {
        Os[w][l15][ 0 + q*4 + r] = f2b(o0[r] * inv);
        Os[w][l15][16 + q*4 + r] = f2b(o1[r] * inv);
        Os[w][l15][32 + q*4 + r] = f2b(o2[r] * inv);
        Os[w][l15][48 + q*4 + r] = f2b(o3[r] * inv);
    }
    __syncthreads();
    int rr = lane >> 2, cc = lane & 3;
    uint4 a0 = *(const uint4*)&Os[w][rr][cc*16];
    uint4 a1 = *(const uint4*)&Os[w][rr][cc*16 + 8];
    size_t orow = ((size_t)b*2048 + i0 + w*16 + rr)*768 + h*64 + cc*16;
    *(uint4*)(attnout + orow)     = a0;
    *(uint4*)(attnout + orow + 8) = a1;
}

extern "C" void kernel_launch(void* const* d_in, const int* in_sizes, int n_in,
                              void* d_out, int out_size, void* d_ws, size_t ws_size,
                              hipStream_t stream) {
    (void)in_sizes; (void)n_in; (void)out_size; (void)ws_size;
    const float* x      = (const float*)d_in[0];
    const int*   dist   = (const int*)d_in[1];
    const int*   mask   = (const int*)d_in[2];
    const float* qkv_w  = (const float*)d_in[3];
    const float* qkv_b  = (const float*)d_in[4];
    const float* out_w  = (const float*)d_in[5];
    const float* out_b  = (const float*)d_in[6];
    const float* btab   = (const float*)d_in[7];
    float* out = (float*)d_out;

    char* ws = (char*)d_ws;
    size_t off = 0;
    auto alloc = [&](size_t bytes) { void* p = ws + off; off += (bytes + 255) & ~(size_t)255; return p; };
    u16* xb      = (u16*)alloc((size_t)4096*768*2);
    u16* wqkvT   = (u16*)alloc((size_t)2304*768*2);
    u16* woutT   = (u16*)alloc((size_t)768*768*2);
    u16* Qb      = (u16*)alloc((size_t)24*2048*64*2);
    u16* Kb      = (u16*)alloc((size_t)24*2048*64*2);
    u16* Vtp     = (u16*)alloc((size_t)24*2048*64*2);
    u16* attnout = (u16*)alloc((size_t)4096*768*2);
    unsigned char* dist8 = (unsigned char*)alloc((size_t)2*2048*2048);

    prep<<<8192 + 1536 + 432 + 144, 256, 0, stream>>>(
        x, xb, qkv_w, wqkvT, out_w, woutT, dist, (const unsigned*)mask, dist8);
    gemmQKV<<<dim3(18,32), 256, 0, stream>>>(xb, wqkvT, qkv_b, Qb, Kb, Vtp);
    flashAttn<<<dim3(32,12,2), 256, 0, stream>>>(Qb, Kb, Vtp, dist8, btab, attnout);
    gemmOut<<<dim3(12,64), 256, 0, stream>>>(attnout, woutT, out_b, out);
}

// Round 16
// 212.680 us; speedup vs baseline: 1.0938x; 1.0082x over previous
//
#include <hip/hip_runtime.h>
#include <hip/hip_bf16.h>

typedef unsigned short u16;
typedef __attribute__((ext_vector_type(8))) short bf16x8;
typedef __attribute__((ext_vector_type(4))) short bf16x4;
typedef __attribute__((ext_vector_type(4))) float f32x4;

#define MFMA_BF16(a,b,c) __builtin_amdgcn_mfma_f32_16x16x32_bf16((a),(b),(c),0,0,0)
#define LOG2E 1.4426950408889634f

// K=16 bf16 MFMA: B-frag layout B[k=q*4+r][col=l15] == our P C-layout, so PV
// needs NO cross-lane exchange. Guarded: fall back to K32+bpermute if absent.
#if __has_builtin(__builtin_amdgcn_mfma_f32_16x16x16bf16_1k)
#define MFMA16(a,b,c) __builtin_amdgcn_mfma_f32_16x16x16bf16_1k((a),(b),(c),0,0,0)
#define HAVE_MFMA16 1
#elif __has_builtin(__builtin_amdgcn_mfma_f32_16x16x16_bf16)
#define MFMA16(a,b,c) __builtin_amdgcn_mfma_f32_16x16x16_bf16((a),(b),(c),0,0,0)
#define HAVE_MFMA16 1
#else
#define HAVE_MFMA16 0
#endif

__device__ __forceinline__ u16 f2b(float f) {
    __hip_bfloat16 h = __float2bfloat16(f);
    u16 u; __builtin_memcpy(&u, &h, 2); return u;
}
__device__ __forceinline__ f32x4 zero4() { f32x4 z = {0.f,0.f,0.f,0.f}; return z; }

// async global->LDS, 16B per lane. LDS dest = wave-uniform base + lane*16.
__device__ __forceinline__ void gl_lds16(const u16* g, u16* l) {
    __builtin_amdgcn_global_load_lds(
        (const __attribute__((address_space(1))) unsigned int*)g,
        (__attribute__((address_space(3))) unsigned int*)l,
        16, 0, 0);
}

// ------ fused preprocessing: packDist(+mask detect) | convX | convTW x2 ------
// dist8 stores dd*4 (byte offset into the f32 bias table); masked (b,j) -> 128.
__global__ __launch_bounds__(256)
void prep(const float* __restrict__ x, u16* __restrict__ xb,
          const float* __restrict__ qkv_w, u16* __restrict__ wqkvT,
          const float* __restrict__ out_w, u16* __restrict__ woutT,
          const int* __restrict__ dist, const unsigned* __restrict__ mask,
          unsigned char* __restrict__ dist8) {
    __shared__ __align__(16) u16 T[64][68];
    __shared__ int sB, sH, sF;
    const int bid = blockIdx.x;
    const int tid = threadIdx.x;
    if (bid < 8192) {
        // ---- packDist: dist int32 -> u8 (dd*4, clipped); masked -> 128 ----
        if (tid == 0) { sB = 0; sH = 0; sF = 0; }
        __syncthreads();
        int lb = 0, lh = 0, lf = 0;
#pragma unroll
        for (int i = 0; i < 4; ++i) {
            unsigned v = mask[tid + i * 256];          // first 4KB: safe under all encodings
            if (v == 0x3f800000u) { lf = 1; }
            else if (v > 1u) {
                unsigned b0 = v & 0xffu, b1 = (v >> 8) & 0xffu, b2 = (v >> 16) & 0xffu, b3 = v >> 24;
                bool bytesOK = (b0 <= 1u) && (b1 <= 1u) && (b2 <= 1u) && (b3 <= 1u);
                unsigned h0 = v & 0xffffu, h1 = v >> 16;
                bool halfOK = (h0 == 0u || h0 == 0x3f80u) && (h1 == 0u || h1 == 0x3f80u);
                if (bytesOK) lb = 1; else if (halfOK) lh = 1;
            }
        }
        if (lb) atomicOr(&sB, 1);
        if (lh) atomicOr(&sH, 1);
        if (lf) atomicOr(&sF, 1);
        __syncthreads();
        int mode = sH ? 3 : (sB ? 1 : (sF ? 2 : 0));
        size_t i = ((size_t)bid * 256 + tid) * 4;
        int4 v = *(const int4*)(dist + i);
        int b = (int)(i >> 22), j = (int)(i & 2047);   // j multiple of 4, no row crossing
        int base = b * 2048 + j;
        int mk0, mk1, mk2, mk3;
        if (mode == 0) {
            int4 mv = *(const int4*)((const int*)mask + base);
            mk0 = mv.x != 0; mk1 = mv.y != 0; mk2 = mv.z != 0; mk3 = mv.w != 0;
        } else if (mode == 1) {
            const unsigned char* m8 = (const unsigned char*)mask;
            mk0 = m8[base] != 0; mk1 = m8[base+1] != 0; mk2 = m8[base+2] != 0; mk3 = m8[base+3] != 0;
        } else if (mode == 2) {
            float4 mv = *(const float4*)((const float*)mask + base);
            mk0 = mv.x != 0.f; mk1 = mv.y != 0.f; mk2 = mv.z != 0.f; mk3 = mv.w != 0.f;
        } else {
            const u16* mh = (const u16*)mask;
            mk0 = mh[base] != 0; mk1 = mh[base+1] != 0; mk2 = mh[base+2] != 0; mk3 = mh[base+3] != 0;
        }
        uchar4 o;
        o.x = mk0 ? 128 : (unsigned char)(min(max(v.x, 0), 31) * 4);
        o.y = mk1 ? 128 : (unsigned char)(min(max(v.y, 0), 31) * 4);
        o.z = mk2 ? 128 : (unsigned char)(min(max(v.z, 0), 31) * 4);
        o.w = mk3 ? 128 : (unsigned char)(min(max(v.w, 0), 31) * 4);
        *(uchar4*)(dist8 + i) = o;
    } else if (bid < 8192 + 1536) {
        // ---- convX: x f32 -> bf16, 8 elems/thread ----
        size_t i = ((size_t)(bid - 8192) * 256 + tid) * 8;
        float4 a = *(const float4*)(x + i);
        float4 b = *(const float4*)(x + i + 4);
        union { u16 s[8]; uint4 v; } u;
        u.s[0]=f2b(a.x); u.s[1]=f2b(a.y); u.s[2]=f2b(a.z); u.s[3]=f2b(a.w);
        u.s[4]=f2b(b.x); u.s[5]=f2b(b.y); u.s[6]=f2b(b.z); u.s[7]=f2b(b.w);
        *(uint4*)(xb + i) = u.v;
    } else {
        // ---- convTW: weight [768][C] f32 -> [C][768] bf16 transpose+convert ----
        const float* in; u16* out; int C, c0, k0;
        if (bid < 8192 + 1536 + 432) {
            int s = bid - (8192 + 1536);
            in = qkv_w; out = wqkvT; C = 2304;
            c0 = (s % 36) * 64; k0 = (s / 36) * 64;
        } else {
            int s = bid - (8192 + 1536 + 432);
            in = out_w; out = woutT; C = 768;
            c0 = (s % 12) * 64; k0 = (s / 12) * 64;
        }
#pragma unroll
        for (int i = 0; i < 4; ++i) {
            int id = tid + i * 256;
            int row = id >> 4, ch = id & 15;
            float4 v = *(const float4*)(in + (size_t)(k0 + row) * C + c0 + ch * 4);
            T[row][ch*4+0] = f2b(v.x); T[row][ch*4+1] = f2b(v.y);
            T[row][ch*4+2] = f2b(v.z); T[row][ch*4+3] = f2b(v.w);
        }
        __syncthreads();
#pragma unroll
        for (int i = 0; i < 2; ++i) {
            int id = tid + i * 256;
            int c = id >> 3, ch = id & 7;
            union { u16 s[8]; uint4 v; } u;
#pragma unroll
            for (int jj = 0; jj < 8; ++jj) u.s[jj] = T[ch*8+jj][c];
            *(uint4*)(out + (size_t)(c0 + c) * 768 + k0 + ch * 8) = u.v;
        }
    }
}

// ------ QKV GEMM: 128x128 tile, 512 threads (8 waves) -- latency-hiding ------
// __syncthreads drains vmcnt(0) (HIP semantics), so every K-step pays the
// full DMA latency minus compute; at 576 blocks x 4 waves = 9 waves/CU there
// was nothing to hide it with. Same tile + same sync structure re-partitioned
// over 8 waves (64x32 sub-tile each, 1 gl_lds16/thread/matrix/step, identical
// lane->row/chunk mapping so the proven swizzle pair is unchanged) -> 18
// waves/CU. XCD swizzle (chunk 72) and vectorized epilogues kept.
__global__ __launch_bounds__(512)
void gemmQKV(const u16* __restrict__ A, const u16* __restrict__ Bt,
             const float* __restrict__ bias,
             u16* __restrict__ qO, u16* __restrict__ kO, u16* __restrict__ vO) {
    __shared__ __align__(16) u16 shmem[16384];   // 32KB: As[2][4096] | Bs[2][4096]; aliased as Ls post-loop
    const int K = 768;
    const int tid = threadIdx.x;
    const int lane = tid & 63, w = tid >> 6;     // w in 0..7
    const int wm = w >> 2, wn = w & 3;           // 2 x 4 wave grid: 64-row x 32-col sub-tile
    const int l15 = lane & 15, q = lane >> 4;
    // XCD-locality remap (576 % 8 == 0 -> bijective)
    const int wg0 = blockIdx.x + 18 * blockIdx.y;
    const int nid = (wg0 & 7) * 72 + (wg0 >> 3);
    const int m0 = (nid / 18) * 128, n0 = (nid % 18) * 128;
    // staging: wave w covers tile rows [w*16, w*16+16), 1 call x 16 rows
    const int stRow = lane >> 2;
    const int stChunk = (lane & 3) ^ ((lane >> 3) & 3);
    const u16* Ag = A + (size_t)(m0 + w*16 + stRow) * K + stChunk * 8;
    const u16* Bg = Bt + (size_t)(n0 + w*16 + stRow) * K + stChunk * 8;
    const int fA = (q ^ ((l15 >> 1) & 3)) * 8;   // read-side chunk swizzle

    f32x4 acc[4][2];
#pragma unroll
    for (int i=0;i<4;++i)
#pragma unroll
        for (int j=0;j<2;++j) acc[i][j] = zero4();

    // prologue: stage kt=0 into buf 0
    gl_lds16(Ag, shmem + w*512);
    gl_lds16(Bg, shmem + 8192 + w*512);
    __syncthreads();

    int cur = 0;
    for (int kt = 0; kt < 24; ++kt) {
        if (kt < 23) {
            const int ko = (kt + 1) * 32;
            gl_lds16(Ag + ko, shmem + (cur^1)*4096 + w*512);
            gl_lds16(Bg + ko, shmem + 8192 + (cur^1)*4096 + w*512);
        }
        const u16* as = shmem + cur*4096;
        const u16* bs = shmem + 8192 + cur*4096;
        bf16x8 af[4], bfr[2];
#pragma unroll
        for (int mt=0; mt<4; ++mt) af[mt]  = *(const bf16x8*)(as + (wm*64+mt*16+l15)*32 + fA);
#pragma unroll
        for (int nt=0; nt<2; ++nt) bfr[nt] = *(const bf16x8*)(bs + (wn*32+nt*16+l15)*32 + fA);
#pragma unroll
        for (int mt=0; mt<4; ++mt)
#pragma unroll
            for (int nt=0; nt<2; ++nt)
                acc[mt][nt] = MFMA_BF16(af[mt], bfr[nt], acc[mt][nt]);
        __syncthreads();
        cur ^= 1;
    }

    const int which = n0 / 768;                  // block-uniform (128 | 768)
    const int b = m0 >> 11, tokB = m0 & 2047;
    if (which == 2) {
        // V: direct transposed 8B stores (proven)
#pragma unroll
        for (int mt=0; mt<4; ++mt) {
#pragma unroll
            for (int nt=0; nt<2; ++nt) {
                int n = n0 + wn*32 + nt*16 + l15;
                int rem = n - 1536;
                int hh = rem >> 6, hd = rem & 63;
                float bv = bias[n];
                int tok0 = tokB + wm*64 + mt*16 + q*4;
                union { u16 s4[4]; unsigned long long u; } pv;
#pragma unroll
                for (int r=0; r<4; ++r) pv.s4[r] = f2b(acc[mt][nt][r] + bv);
                *(unsigned long long*)(vO + ((size_t)(b*12 + hh)*64 + hd)*2048 + tok0) = pv.u;
            }
        }
    } else {
        // Q/K: bounce acc -> Ls (aliases dead staging LDS), coalesced uint4 stores
        const float sc = (which == 0) ? (0.125f * LOG2E) : 1.0f;
        u16* Ls = shmem;                         // [128][128] u16 = 32KB exactly
#pragma unroll
        for (int mt=0; mt<4; ++mt) {
#pragma unroll
            for (int nt=0; nt<2; ++nt) {
                int col = wn*32 + nt*16 + l15;
                float bv = bias[n0 + col];
#pragma unroll
                for (int r=0; r<4; ++r)
                    Ls[(wm*64 + mt*16 + q*4 + r)*128 + col] = f2b((acc[mt][nt][r] + bv) * sc);
            }
        }
        __syncthreads();
        u16* dst = (which == 0) ? qO : kO;
        const int h0 = (n0 - which*768) >> 6;    // 2 heads per 128-wide tile
#pragma unroll
        for (int k = 0; k < 4; ++k) {
            int idx = k*512 + tid;               // 2048 uint4 total
            int row = idx >> 4, rem = idx & 15;
            int hh = rem >> 3, c = rem & 7;
            uint4 v = *(const uint4*)(Ls + row*128 + hh*64 + c*8);
            *(uint4*)(dst + ((size_t)(b*12 + h0 + hh)*2048 + tokB + row)*64 + c*8) = v;
        }
    }
}

// ------ output GEMM: 64x64 tiles + XCD swizzle (chunk 96 = 8m x 12n) ------
__global__ __launch_bounds__(256)
void gemmOut(const u16* __restrict__ A, const u16* __restrict__ Bt,
             const float* __restrict__ bias, float* __restrict__ fO) {
    __shared__ __align__(16) u16 As[2][64*32];
    __shared__ __align__(16) u16 Bs[2][64*32];
    const int K = 768;
    const int tid = threadIdx.x;
    const int lane = tid & 63, w = tid >> 6;
    const int l15 = lane & 15, q = lane >> 4;
    // XCD-locality remap (768 % 8 == 0 -> bijective)
    const int wg0 = blockIdx.x + 12 * blockIdx.y;
    const int nid = (wg0 & 7) * 96 + (wg0 >> 3);
    const int m0 = (nid / 12) * 64, n0 = (nid % 12) * 64;
    const int stRow = tid >> 2;                        // 0..63
    const int stChunk = (tid & 3) ^ ((tid >> 3) & 3);  // XOR by (row>>1)&3
    const u16* Ag = A + (size_t)(m0 + stRow) * K + stChunk * 8;
    const u16* Bg = Bt + (size_t)(n0 + stRow) * K + stChunk * 8;
    const int fA = (q ^ ((l15 >> 1) & 3)) * 8;

    f32x4 acc[4];
#pragma unroll
    for (int i=0;i<4;++i) acc[i] = zero4();

    gl_lds16(Ag, &As[0][0] + w*512);
    gl_lds16(Bg, &Bs[0][0] + w*512);
    __syncthreads();

    int cur = 0;
    for (int kt = 0; kt < 24; ++kt) {
        if (kt < 23) {
            const int ko = (kt + 1) * 32;
            gl_lds16(Ag + ko, &As[cur^1][0] + w*512);
            gl_lds16(Bg + ko, &Bs[cur^1][0] + w*512);
        }
        const u16* as = &As[cur][0];
        const u16* bs = &Bs[cur][0];
        bf16x8 af = *(const bf16x8*)(as + (w*16 + l15)*32 + fA);
        bf16x8 bfr[4];
#pragma unroll
        for (int nt=0; nt<4; ++nt) bfr[nt] = *(const bf16x8*)(bs + (nt*16+l15)*32 + fA);
#pragma unroll
        for (int nt=0; nt<4; ++nt) acc[nt] = MFMA_BF16(af, bfr[nt], acc[nt]);
        __syncthreads();
        cur ^= 1;
    }

#pragma unroll
    for (int nt=0; nt<4; ++nt) {
        int n = n0 + nt*16 + l15;
        float bv = bias[n];
#pragma unroll
        for (int r=0; r<4; ++r) {
            int m = m0 + w*16 + q*4 + r;
            fO[(size_t)m*768 + n] = acc[nt][r] + bv;
        }
    }
}

// ------ fused flash attention: LDS-staged K/V/dist, single-pass, K16-MFMA PV ------
// (byte-identical to round 14's ~80us kernel)
__global__ __launch_bounds__(256)
void flashAttn(const u16* __restrict__ Qb, const u16* __restrict__ Kb,
               const u16* __restrict__ Vt, const unsigned char* __restrict__ dist8,
               const float* __restrict__ btg, u16* __restrict__ attnout) {
    __shared__ float bt[33];
    __shared__ __align__(16) u16 KT[2][4096];   // [buf][64 j][64 d] swizzled
    __shared__ __align__(16) u16 VT[2][4096];   // [buf][64 d][64 j] swizzled
    __shared__ __align__(16) u16 DT[2][2048];   // [buf][64 i][64 j] u8, swizzled
    __shared__ __align__(16) u16 Os[4][16][72];
    const int tid = threadIdx.x;
    const int lane = tid & 63, w = tid >> 6;
    const int l15 = lane & 15, q = lane >> 4;
    // --- XCD-locality remap (bijective on [0,768)) ---
    const int wg = blockIdx.x + 32 * (blockIdx.y + 12 * blockIdx.z);
    const int xcd = wg & 7, slot = wg >> 3;
    const int g = ((slot >> 5) << 3) + xcd;            // group = (b,h), [0,24)
    const int i0 = (slot & 31) * 64;                   // i-block within group
    const int b = g / 12, h = g - b * 12;
    const int bh = g;
    const float NEG_INF = -__builtin_inff();
    if (tid < 33) bt[tid] = (tid == 32) ? NEG_INF : btg[tid*12 + h] * LOG2E;

    const int iRow = i0 + w*16 + l15;
    const u16* Qp = Qb + ((size_t)bh*2048 + iRow)*64;
    bf16x8 qB0 = *(const bf16x8*)(Qp + q*8);
    bf16x8 qB1 = *(const bf16x8*)(Qp + 32 + q*8);
#if !HAVE_MFMA16
    const int srcL0 = ((2*q)   & 3)*16 + l15;
    const int srcL1 = ((2*q+1) & 3)*16 + l15;
    union { unsigned u4[4]; bf16x8 v; } one_;
    { unsigned oc = (l15 == 0) ? 0x3F803F80u : 0u;
      one_.u4[0]=oc; one_.u4[1]=oc; one_.u4[2]=oc; one_.u4[3]=oc; }
#else
    union { unsigned u2[2]; bf16x4 v; } one4_;
    { unsigned oc = (l15 == 0) ? 0x3F803F80u : 0u;
      one4_.u2[0]=oc; one4_.u2[1]=oc; }
#endif

    // --- staging geometry: LDS linear dest, XOR-swizzled source ---
    const int stRow = w*16 + (lane >> 3);                       // K/V: + c*8
    const int stCol = (((lane & 7) ^ (lane >> 3)) << 4);        // K/V 16B chunk
    const int dRow = w*16 + (lane >> 2);                        // dist: 64 rows
    const int dCol = ((lane & 3) ^ ((lane >> 3) & 3)) << 4;     // dist 16B chunk
    const char* kgB = (const char*)Kb + (size_t)bh*2048*128;    // [tok][64d*2B]
    const char* vgB = (const char*)Vt + (size_t)bh*64*4096;     // [d][2048tok*2B]
    const unsigned char* dgB = dist8 + (size_t)(b*2048 + i0)*2048;
    const int swz = (l15 & 7) << 4;
    const int f0 = (q*16)      ^ swz;
    const int f1 = (q*16 + 64) ^ swz;
    const int rB = l15 * 128;
    const int rD = (w*16 + l15) * 64;                           // dist row base
    const int dsw = (l15 >> 1) & 3;                             // dist read swizzle

    // prologue: stage tile 0 into buf 0
    {
        u16* kd = &KT[0][0] + w*1024;
        u16* vd = &VT[0][0] + w*1024;
#pragma unroll
        for (int c = 0; c < 2; ++c) {
            int row = stRow + c*8;
            gl_lds16((const u16*)(kgB + (size_t)row*128 + stCol),  kd + c*512);
            gl_lds16((const u16*)(vgB + (size_t)row*4096 + stCol), vd + c*512);
        }
        gl_lds16((const u16*)(dgB + (size_t)dRow*2048 + dCol),
                 (u16*)((char*)&DT[0][0] + w*1024));
    }
    __syncthreads();

    f32x4 o0 = zero4(), o1 = zero4(), o2 = zero4(), o3 = zero4(), o4 = zero4();
    float mI = NEG_INF;
    int cur = 0;

    for (int jt = 0; jt < 32; ++jt) {
        const int j0 = jt * 64;
        // --- issue next tile's DMA first (hides under compute) ---
        if (jt < 31) {
            const int j0n = j0 + 64;
            u16* kd = &KT[cur^1][0] + w*1024;
            u16* vd = &VT[cur^1][0] + w*1024;
#pragma unroll
            for (int c = 0; c < 2; ++c) {
                int row = stRow + c*8;
                gl_lds16((const u16*)(kgB + (size_t)(j0n + row)*128 + stCol),          kd + c*512);
                gl_lds16((const u16*)(vgB + (size_t)row*4096 + (size_t)j0n*2 + stCol), vd + c*512);
            }
            gl_lds16((const u16*)(dgB + (size_t)dRow*2048 + j0n + dCol),
                     (u16*)((char*)&DT[cur^1][0] + w*1024));
        }
        // dist byte-offsets from LDS (swizzled)
        const char* dt = (const char*)&DT[cur][0];
        unsigned dv4[4];
#pragma unroll
        for (int mt = 0; mt < 4; ++mt)
            dv4[mt] = *(const unsigned*)(dt + rD + ((mt ^ dsw) << 4) + q*4);

        // --- S^T = K·Q^T from LDS ---
        const char* kt = (const char*)&KT[cur][0];
        f32x4 s0 = zero4(), s1 = zero4(), s2 = zero4(), s3 = zero4();
        {
            bf16x8 k00 = *(const bf16x8*)(kt + rB          + f0);
            bf16x8 k01 = *(const bf16x8*)(kt + rB          + f1);
            bf16x8 k10 = *(const bf16x8*)(kt + rB + 2048   + f0);
            bf16x8 k11 = *(const bf16x8*)(kt + rB + 2048   + f1);
            bf16x8 k20 = *(const bf16x8*)(kt + rB + 4096   + f0);
            bf16x8 k21 = *(const bf16x8*)(kt + rB + 4096   + f1);
            bf16x8 k30 = *(const bf16x8*)(kt + rB + 6144   + f0);
            bf16x8 k31 = *(const bf16x8*)(kt + rB + 6144   + f1);
            __builtin_amdgcn_s_setprio(1);
            s0 = MFMA_BF16(k00, qB0, s0); s0 = MFMA_BF16(k01, qB1, s0);
            s1 = MFMA_BF16(k10, qB0, s1); s1 = MFMA_BF16(k11, qB1, s1);
            s2 = MFMA_BF16(k20, qB0, s2); s2 = MFMA_BF16(k21, qB1, s2);
            s3 = MFMA_BF16(k30, qB0, s3); s3 = MFMA_BF16(k31, qB1, s3);
            __builtin_amdgcn_s_setprio(0);
        }

        // --- bias gather (dd = byte offset; 128 -> -inf) applies mask too ---
        float sv[4][4];
#pragma unroll
        for (int mt = 0; mt < 4; ++mt) {
            const f32x4 sm = mt==0 ? s0 : (mt==1 ? s1 : (mt==2 ? s2 : s3));
            const unsigned d4 = dv4[mt];
#pragma unroll
            for (int r = 0; r < 4; ++r) {
                unsigned dd = (d4 >> (r*8)) & 255u;
                float btv = *(const float*)((const char*)bt + dd);
                sv[mt][r] = sm[r] + btv;
            }
        }

        // --- online max (tree + 2 cross-quad shfl) + THRESHOLD defer-rescale ---
        float t0 = fmaxf(fmaxf(sv[0][0], sv[0][1]), fmaxf(sv[0][2], sv[0][3]));
        float t1 = fmaxf(fmaxf(sv[1][0], sv[1][1]), fmaxf(sv[1][2], sv[1][3]));
        float t2 = fmaxf(fmaxf(sv[2][0], sv[2][1]), fmaxf(sv[2][2], sv[2][3]));
        float t3 = fmaxf(fmaxf(sv[3][0], sv[3][1]), fmaxf(sv[3][2], sv[3][3]));
        float rm = fmaxf(fmaxf(t0, t1), fmaxf(t2, t3));
        rm = fmaxf(rm, __shfl_xor(rm, 16, 64));
        rm = fmaxf(rm, __shfl_xor(rm, 32, 64));
        if (!__all(rm <= mI + 8.0f)) {               // T13: P bounded by 2^8
            float mn = fmaxf(mI, rm);
            float al = exp2f(mI - mn);
            mI = mn;
#pragma unroll
            for (int r = 0; r < 4; ++r) { o0[r] *= al; o1[r] *= al; o2[r] *= al; o3[r] *= al; }
            o4[0] *= al;
        }
        float p[4][4];
#pragma unroll
        for (int mt = 0; mt < 4; ++mt)
#pragma unroll
            for (int r = 0; r < 4; ++r) p[mt][r] = exp2f(sv[mt][r] - mI);

        const char* vt = (const char*)&VT[cur][0];
#if HAVE_MFMA16
        // --- pack P (C-layout == K16 B-frag layout) and PV, no exchange ---
        __builtin_amdgcn_s_setprio(1);
#pragma unroll
        for (int mt = 0; mt < 4; ++mt) {
            union { unsigned d[2]; bf16x4 v; } pu;
            pu.d[0] = (unsigned)f2b(p[mt][0]) | ((unsigned)f2b(p[mt][1]) << 16);
            pu.d[1] = (unsigned)f2b(p[mt][2]) | ((unsigned)f2b(p[mt][3]) << 16);
            const int cbase = (((mt*2 + (q>>1)) ^ (l15 & 7)) << 4) + (q & 1)*8;
            bf16x4 v0 = *(const bf16x4*)(vt + rB          + cbase);
            bf16x4 v1 = *(const bf16x4*)(vt + rB + 2048   + cbase);
            bf16x4 v2 = *(const bf16x4*)(vt + rB + 4096   + cbase);
            bf16x4 v3 = *(const bf16x4*)(vt + rB + 6144   + cbase);
            o0 = MFMA16(v0, pu.v, o0);
            o1 = MFMA16(v1, pu.v, o1);
            o2 = MFMA16(v2, pu.v, o2);
            o3 = MFMA16(v3, pu.v, o3);
            o4 = MFMA16(one4_.v, pu.v, o4);
        }
        __builtin_amdgcn_s_setprio(0);
#else
        // --- fallback: pack, exchange (16 bpermute + 8 select), K32 PV ---
        unsigned pk[4][2];
#pragma unroll
        for (int mt = 0; mt < 4; ++mt) {
            pk[mt][0] = (unsigned)f2b(p[mt][0]) | ((unsigned)f2b(p[mt][1]) << 16);
            pk[mt][1] = (unsigned)f2b(p[mt][2]) | ((unsigned)f2b(p[mt][3]) << 16);
        }
        __builtin_amdgcn_s_setprio(1);
#pragma unroll
        for (int ks = 0; ks < 2; ++ks) {
            union { unsigned d[4]; bf16x8 v; } pb;
#pragma unroll
            for (int s = 0; s < 4; ++s) {
                int sl = (s >> 1) ? srcL1 : srcL0;
                int u0 = __shfl((int)pk[2*ks    ][s & 1], sl, 64);
                int u1 = __shfl((int)pk[2*ks + 1][s & 1], sl, 64);
                pb.d[s] = (q >> 1) ? (unsigned)u1 : (unsigned)u0;
            }
            const int fk = ks ? f1 : f0;
            bf16x8 v0 = *(const bf16x8*)(vt + rB          + fk);
            bf16x8 v1 = *(const bf16x8*)(vt + rB + 2048   + fk);
            bf16x8 v2 = *(const bf16x8*)(vt + rB + 4096   + fk);
            bf16x8 v3 = *(const bf16x8*)(vt + rB + 6144   + fk);
            o0 = MFMA_BF16(v0, pb.v, o0);
            o1 = MFMA_BF16(v1, pb.v, o1);
            o2 = MFMA_BF16(v2, pb.v, o2);
            o3 = MFMA_BF16(v3, pb.v, o3);
            o4 = MFMA_BF16(one_.v, pb.v, o4);
        }
        __builtin_amdgcn_s_setprio(0);
#endif

        __syncthreads();   // drains staging DMA + joins waves
        cur ^= 1;
    }

    // --- epilogue: denominator from ones-row (C row 0, lanes q==0) ---
    float lsum = __shfl(o4[0], l15, 64);
    float inv = 1.0f / lsum;
#pragma unroll
    for (int r = 0; r < 4; ++r) {
        Os[w][l15][ 0 + q*4 + r] = f2b(o0[r] * inv);
        Os[w][l15][16 + q*4 + r] = f2b(o1[r] * inv);
        Os[w][l15][32 + q*4 + r] = f2b(o2[r] * inv);
        Os[w][l15][48 + q*4 + r] = f2b(o3[r] * inv);
    }
    __syncthreads();
    int rr = lane >> 2, cc = lane & 3;
    uint4 a0 = *(const uint4*)&Os[w][rr][cc*16];
    uint4 a1 = *(const uint4*)&Os[w][rr][cc*16 + 8];
    size_t orow = ((size_t)b*2048 + i0 + w*16 + rr)*768 + h*64 + cc*16;
    *(uint4*)(attnout + orow)     = a0;
    *(uint4*)(attnout + orow + 8) = a1;
}

extern "C" void kernel_launch(void* const* d_in, const int* in_sizes, int n_in,
                              void* d_out, int out_size, void* d_ws, size_t ws_size,
                              hipStream_t stream) {
    (void)in_sizes; (void)n_in; (void)out_size; (void)ws_size;
    const float* x      = (const float*)d_in[0];
    const int*   dist   = (const int*)d_in[1];
    const int*   mask   = (const int*)d_in[2];
    const float* qkv_w  = (const float*)d_in[3];
    const float* qkv_b  = (const float*)d_in[4];
    const float* out_w  = (const float*)d_in[5];
    const float* out_b  = (const float*)d_in[6];
    const float* btab   = (const float*)d_in[7];
    float* out = (float*)d_out;

    char* ws = (char*)d_ws;
    size_t off = 0;
    auto alloc = [&](size_t bytes) { void* p = ws + off; off += (bytes + 255) & ~(size_t)255; return p; };
    u16* xb      = (u16*)alloc((size_t)4096*768*2);
    u16* wqkvT   = (u16*)alloc((size_t)2304*768*2);
    u16* woutT   = (u16*)alloc((size_t)768*768*2);
    u16* Qb      = (u16*)alloc((size_t)24*2048*64*2);
    u16* Kb      = (u16*)alloc((size_t)24*2048*64*2);
    u16* Vtp     = (u16*)alloc((size_t)24*2048*64*2);
    u16* attnout = (u16*)alloc((size_t)4096*768*2);
    unsigned char* dist8 = (unsigned char*)alloc((size_t)2*2048*2048);

    prep<<<8192 + 1536 + 432 + 144, 256, 0, stream>>>(
        x, xb, qkv_w, wqkvT, out_w, woutT, dist, (const unsigned*)mask, dist8);
    gemmQKV<<<dim3(18,32), 512, 0, stream>>>(xb, wqkvT, qkv_b, Qb, Kb, Vtp);
    flashAttn<<<dim3(32,12,2), 256, 0, stream>>>(Qb, Kb, Vtp, dist8, btab, attnout);
    gemmOut<<<dim3(12,64), 256, 0, stream>>>(attnout, woutT, out_b, out);
}